// Round 2
// baseline (46230.887 us; speedup 1.0000x reference)
//
#include <hip/hip_runtime.h>
#include <stdint.h>

// ---------------------------------------------------------------------------
// trajectory2seq_attn — persistent-kernel rewrite (round 2).
// Encoder: ONE kernel, 513 epochs, grid barrier per epoch.
// Decoder: ONE kernel, 64 steps x 7 phases, grid barrier per phase.
// Precision: fp16 hi/lo split GEMMs (3 MFMA, fp32 accum) everywhere.
// ---------------------------------------------------------------------------

#define BB 64
#define SS 512
#define TT 64
#define HH 1024
#define VV 1024
#define BH 65536   // B*H
#define SH 524288  // S*H
#define OFF_HID  4194304           // B*T*V
#define OFF_ATTN 4325376           // + L*B*H

typedef _Float16 half8  __attribute__((ext_vector_type(8)));
typedef float    floatx4 __attribute__((ext_vector_type(4)));

struct P {
  const float *x, *emb;
  const float *eWih0, *eWhh0, *ebih0, *ebhh0;
  const float *dWih0, *dWhh0, *dbih0, *dbhh0;
  const float *eWih1, *eWhh1, *ebih1, *ebhh1;
  const float *dWih1, *dWhh1, *dbih1, *dbhh1;
  const float *hqW, *hqb, *combW, *combb, *fcW, *fcb;
  uint32_t* enc_i;                 // [B][S][H] packed (hi | lo<<16)
  _Float16 *W0h,*W0l;              // enc l0 Whh grouped [128][24][1024]
  _Float16 *W1h,*W1l;              // enc l1 [Whh1|Wih1] grouped [128][24][2048]
  _Float16 *embh,*embl,*T0h,*T0l;  // T0 = emb @ dWih0^T + dbih0  [V][H] pairs
  _Float16 *wih0dh,*wih0dl,*wih1dh,*wih1dl,*whh0dh,*whh0dl,*whh1dh,*whh1dl;
  _Float16 *hqh,*hql,*combh,*combl,*fch,*fcl;
  _Float16 *h0h,*h0l,*h1h,*h1l;    // [2][B*H] parity-double-buffered enc states
  _Float16 *dh0h,*dh0l,*dh1h,*dh1l;// decoder states [B*H]
  _Float16 *cath,*catl;            // [B][2048] = [h1 | att] pairs
  _Float16 *ch,*cl;                // comb output pairs [B*H]
  float *u0,*u1,*q;                // fp32 [B*H]
  float *attp_o;                   // [B][4][H]
  float *attp_ml;                  // [B][4][2]
  float *sc63;                     // [B][S] raw scores at t=63
  unsigned long long* amax;        // [B][128] argmax partials
  unsigned *bar0, *bar1;           // grid-barrier counters (enc, dec)
  float* dout;
};

// ---------------- helpers ----------------
__device__ __forceinline__ void splitf(float x, _Float16& hi, _Float16& lo){
  _Float16 h = (_Float16)x; hi = h;
  lo = (_Float16)((x - (float)h) * 2048.0f);
}
__device__ __forceinline__ float reconf(_Float16 hi, _Float16 lo){
  return fmaf((float)lo, 1.0f/2048.0f, (float)hi);
}
__device__ __forceinline__ float recon_u32(uint32_t w){
  float hi = (float)__builtin_bit_cast(_Float16, (unsigned short)(w & 0xffffu));
  float lo = (float)__builtin_bit_cast(_Float16, (unsigned short)(w >> 16));
  return fmaf(lo, 1.0f/2048.0f, hi);
}
__device__ __forceinline__ uint32_t pack_pair(float x){
  _Float16 hi, lo; splitf(x, hi, lo);
  return (uint32_t)__builtin_bit_cast(unsigned short, hi)
       | ((uint32_t)__builtin_bit_cast(unsigned short, lo) << 16);
}
__device__ __forceinline__ unsigned ordf(float f){
  unsigned u = __float_as_uint(f);
  return (u & 0x80000000u) ? ~u : (u | 0x80000000u);
}

// Grid barrier: monotonic counter, one add per block, agent-scope (L2-bypass).
// __syncthreads drains each wave's vmem stores before the add; __threadfence
// (agent seq_cst) does the L2 writeback / invalidate around the rendezvous.
__device__ __forceinline__ void gbar(unsigned* c, unsigned target){
  __syncthreads();
  if (threadIdx.x == 0){
    __threadfence();
    __hip_atomic_fetch_add(c, 1u, __ATOMIC_RELAXED, __HIP_MEMORY_SCOPE_AGENT);
    while (__hip_atomic_load(c, __ATOMIC_RELAXED, __HIP_MEMORY_SCOPE_AGENT) < target)
      __builtin_amdgcn_s_sleep(4);
    __threadfence();
  }
  __syncthreads();
}

// ---------------- split-precision GEMM core (used by k_t0 only) ----------------
template<int NT, int KH, bool SPLIT>
__device__ __forceinline__ void gemm_core(
    const _Float16* __restrict__ Ah0, const _Float16* __restrict__ Al0,
    const _Float16* __restrict__ Ah1, const _Float16* __restrict__ Al1,
    int sA,
    const _Float16* __restrict__ Wh, const _Float16* __restrict__ Wl,
    int nrows, _Float16* ldsW, float* accOut)
{
  const int tid = threadIdx.x, lane = tid & 63, wave = tid >> 6;
  const int mA = (wave<<4) + (lane & 15);
  const int kb = ((lane>>4) << 3);
  const int wstride = KH << 10;
  floatx4 aH[NT], aM1[NT], aM2[NT];
  int ne[NT];
  const _Float16* bh_base[NT];
  const _Float16* bl_base[NT];
  #pragma unroll
  for (int nt=0; nt<NT; ++nt){
    int nn = (lane & 15) + (nt<<4);
    ne[nt] = nn < nrows ? nn : nrows - 1;
    bh_base[nt] = ldsW + ne[nt]*1032 + kb;
    aH[nt]  = floatx4{0.f,0.f,0.f,0.f};
    aM1[nt] = floatx4{0.f,0.f,0.f,0.f};
    aM2[nt] = floatx4{0.f,0.f,0.f,0.f};
  }
  #pragma unroll
  for (int kh=0; kh<KH; ++kh){
    __syncthreads();
    const int iters = (nrows*128 + 255) >> 8;
    for (int it=0; it<iters; ++it){
      int idx = tid + (it<<8);
      int row = idx >> 7, col = (idx & 127) << 3;
      if (row < nrows)
        *(half8*)(ldsW + row*1032 + col) =
            *(const half8*)(Wh + row*wstride + (kh<<10) + col);
    }
    __syncthreads();
    const _Float16* ah_p = ((KH==2 && kh==1) ? Ah1 : Ah0) + mA*sA + kb;
    const _Float16* al_p = ((KH==2 && kh==1) ? Al1 : Al0) + mA*sA + kb;
    #pragma unroll
    for (int nt=0; nt<NT; ++nt) bl_base[nt] = Wl + ne[nt]*wstride + (kh<<10) + kb;
    #pragma unroll 4
    for (int ks=0; ks<32; ++ks){
      half8 ah = *(const half8*)(ah_p + (ks<<5));
      half8 al = *(const half8*)(al_p + (ks<<5));
      #pragma unroll
      for (int nt=0; nt<NT; ++nt){
        half8 bh = *(const half8*)(bh_base[nt] + (ks<<5));
        half8 bl = *(const half8*)(bl_base[nt] + (ks<<5));
        aH[nt]  = __builtin_amdgcn_mfma_f32_16x16x32_f16(ah, bh, aH[nt],  0,0,0);
        aM1[nt] = __builtin_amdgcn_mfma_f32_16x16x32_f16(ah, bl, aM1[nt], 0,0,0);
        aM2[nt] = __builtin_amdgcn_mfma_f32_16x16x32_f16(al, bh, aM2[nt], 0,0,0);
      }
    }
    if (SPLIT){
      #pragma unroll
      for (int nt=0; nt<NT; ++nt){
        #pragma unroll
        for (int r=0;r<4;++r)
          accOut[(kh*NT + nt)*4 + r] = aH[nt][r] + (aM1[nt][r] + aM2[nt][r]) * (1.f/2048.f);
        aH[nt]  = floatx4{0.f,0.f,0.f,0.f};
        aM1[nt] = floatx4{0.f,0.f,0.f,0.f};
        aM2[nt] = floatx4{0.f,0.f,0.f,0.f};
      }
    }
  }
  if (!SPLIT){
    #pragma unroll
    for (int nt=0; nt<NT; ++nt)
      #pragma unroll
      for (int r=0;r<4;++r)
        accOut[nt*4 + r] = aH[nt][r] + (aM1[nt][r] + aM2[nt][r]) * (1.f/2048.f);
  }
}

// ---------------- prologue kernels ----------------
__global__ __launch_bounds__(256) void k_splitall(P p){
  const int M = 1<<20;
  for (int i = blockIdx.x*256 + threadIdx.x; i < 9*M; i += gridDim.x*256){
    const float* s; _Float16 *dh, *dl; int j;
    if      (i <   M){ j=i;     s=p.emb;   dh=p.embh;   dl=p.embl; }
    else if (i < 2*M){ j=i-M;   s=p.dWih0; dh=p.wih0dh; dl=p.wih0dl; }
    else if (i < 3*M){ j=i-2*M; s=p.dWih1; dh=p.wih1dh; dl=p.wih1dl; }
    else if (i < 4*M){ j=i-3*M; s=p.dWhh0; dh=p.whh0dh; dl=p.whh0dl; }
    else if (i < 5*M){ j=i-4*M; s=p.dWhh1; dh=p.whh1dh; dl=p.whh1dl; }
    else if (i < 6*M){ j=i-5*M; s=p.hqW;   dh=p.hqh;    dl=p.hql; }
    else if (i < 8*M){ j=i-6*M; s=p.combW; dh=p.combh;  dl=p.combl; }
    else             { j=i-8*M; s=p.fcW;   dh=p.fch;    dl=p.fcl; }
    _Float16 hi,lo; splitf(s[j],hi,lo); dh[j]=hi; dl[j]=lo;
  }
}

__global__ __launch_bounds__(256) void k_rw0(P p){
  const int n = 128*24*1024;
  for (int i = blockIdx.x*256 + threadIdx.x; i < n; i += gridDim.x*256){
    int k = i & 1023; int rest = i >> 10; int rr = rest % 24; int blk = rest / 24;
    int grow = (rr>>3)*1024 + (blk<<3) + (rr&7);
    _Float16 hi,lo; splitf(p.eWhh0[grow*1024 + k],hi,lo);
    p.W0h[i]=hi; p.W0l[i]=lo;
  }
}
__global__ __launch_bounds__(256) void k_rw1(P p){
  const int n = 128*24*2048;
  for (int i = blockIdx.x*256 + threadIdx.x; i < n; i += gridDim.x*256){
    int k = i & 2047; int rest = i >> 11; int rr = rest % 24; int blk = rest / 24;
    int grow = (rr>>3)*1024 + (blk<<3) + (rr&7);
    float v = (k < 1024) ? p.eWhh1[grow*1024 + k] : p.eWih1[grow*1024 + (k-1024)];
    _Float16 hi,lo; splitf(v,hi,lo);
    p.W1h[i]=hi; p.W1l[i]=lo;
  }
}
__global__ __launch_bounds__(256) void k_zero(P p){
  int i = blockIdx.x*256 + threadIdx.x;   // grid 256 -> 65536 threads
  p.h1h[i] = (_Float16)0.f; p.h1l[i] = (_Float16)0.f;           // h1 parity 0
  p.h0h[BH + i] = (_Float16)0.f; p.h0l[BH + i] = (_Float16)0.f; // h0 parity 1
  if (i == 0){ *p.bar0 = 0u; *p.bar1 = 0u; }
}
// T0[v][j] = emb[v] . dWih0[j] + dbih0[j]
__global__ __launch_bounds__(256) void k_t0(P p){
  __shared__ _Float16 ldsW[16*1032];
  const int ns = blockIdx.x & 63, mc = blockIdx.x >> 6;
  float acc[4];
  gemm_core<1,1,false>(p.embh + mc*65536, p.embl + mc*65536, nullptr, nullptr, 1024,
                       p.wih0dh + ns*16*1024, p.wih0dl + ns*16*1024, 16, ldsW, acc);
  const int lane = threadIdx.x & 63, wave = threadIdx.x >> 6;
  const int n = lane & 15, col = (ns<<4) + n;
  const float bv = p.dbih0[col];
  #pragma unroll
  for (int r=0;r<4;++r){
    int v = mc*64 + (wave<<4) + ((lane>>4)<<2) + r;
    _Float16 hi,lo; splitf(acc[r] + bv, hi, lo);
    p.T0h[v*1024 + col] = hi; p.T0l[v*1024 + col] = lo;
  }
}

// ---------------- streaming fragment GEMM: 2 m-tiles x 2 n-tiles ----------------
// o[nt*8 + mt*4 + r]
template<int KSIT>
__device__ __forceinline__ void frag2(
    const _Float16* __restrict__ a0h, const _Float16* __restrict__ a0l,
    const _Float16* __restrict__ a1h, const _Float16* __restrict__ a1l,
    const _Float16* __restrict__ b0h, const _Float16* __restrict__ b0l,
    const _Float16* __restrict__ b1h, const _Float16* __restrict__ b1l,
    float* o)
{
  floatx4 H00{0,0,0,0},H10{0,0,0,0},H01{0,0,0,0},H11{0,0,0,0};
  floatx4 M00{0,0,0,0},M10{0,0,0,0},M01{0,0,0,0},M11{0,0,0,0};
  floatx4 N00{0,0,0,0},N10{0,0,0,0},N01{0,0,0,0},N11{0,0,0,0};
  #pragma unroll
  for (int ks=0; ks<KSIT; ++ks){
    const int off = ks<<5;
    half8 A0h = *(const half8*)(a0h+off), A0l = *(const half8*)(a0l+off);
    half8 A1h = *(const half8*)(a1h+off), A1l = *(const half8*)(a1l+off);
    half8 B0h = *(const half8*)(b0h+off), B0l = *(const half8*)(b0l+off);
    half8 B1h = *(const half8*)(b1h+off), B1l = *(const half8*)(b1l+off);
    H00 = __builtin_amdgcn_mfma_f32_16x16x32_f16(A0h,B0h,H00,0,0,0);
    M00 = __builtin_amdgcn_mfma_f32_16x16x32_f16(A0h,B0l,M00,0,0,0);
    N00 = __builtin_amdgcn_mfma_f32_16x16x32_f16(A0l,B0h,N00,0,0,0);
    H10 = __builtin_amdgcn_mfma_f32_16x16x32_f16(A1h,B0h,H10,0,0,0);
    M10 = __builtin_amdgcn_mfma_f32_16x16x32_f16(A1h,B0l,M10,0,0,0);
    N10 = __builtin_amdgcn_mfma_f32_16x16x32_f16(A1l,B0h,N10,0,0,0);
    H01 = __builtin_amdgcn_mfma_f32_16x16x32_f16(A0h,B1h,H01,0,0,0);
    M01 = __builtin_amdgcn_mfma_f32_16x16x32_f16(A0h,B1l,M01,0,0,0);
    N01 = __builtin_amdgcn_mfma_f32_16x16x32_f16(A0l,B1h,N01,0,0,0);
    H11 = __builtin_amdgcn_mfma_f32_16x16x32_f16(A1h,B1h,H11,0,0,0);
    M11 = __builtin_amdgcn_mfma_f32_16x16x32_f16(A1h,B1l,M11,0,0,0);
    N11 = __builtin_amdgcn_mfma_f32_16x16x32_f16(A1l,B1h,N11,0,0,0);
  }
  const float s = 1.f/2048.f;
  #pragma unroll
  for (int r=0;r<4;++r){
    o[r]    = H00[r] + (M00[r]+N00[r])*s;
    o[4+r]  = H10[r] + (M10[r]+N10[r])*s;
    o[8+r]  = H01[r] + (M01[r]+N01[r])*s;
    o[12+r] = H11[r] + (M11[r]+N11[r])*s;
  }
}

// ---------------- persistent encoder ----------------
// 256 blocks x 1024 thr. blocks 0..127: layer0 (t=e), 128..255: layer1 (t=e-1).
// 16 waves = mtg(2: m 0-31/32-63) x kg(8 K-slices). One grid barrier per epoch.
__global__ __launch_bounds__(1024) void k_encp(P p){
  const int tid = threadIdx.x, lane = tid & 63, wave = tid >> 6;
  const int mtg = wave & 1, kg = wave >> 1;
  const bool is0 = blockIdx.x < 128;
  const int blk = is0 ? (int)blockIdx.x : (int)blockIdx.x - 128;
  const int j0 = blk << 3;
  __shared__ float ldsA[8][24][68];
  __shared__ float ldsC[24][4];
  if (tid < 24){
    int grow = (tid>>3)*1024 + j0 + (tid & 7);
    if (is0){ ldsC[tid][0]=p.eWih0[grow*2]; ldsC[tid][1]=p.eWih0[grow*2+1];
              ldsC[tid][2]=p.ebih0[grow];   ldsC[tid][3]=p.ebhh0[grow]; }
    else    { ldsC[tid][0]=p.ebih1[grow];   ldsC[tid][1]=p.ebhh1[grow]; }
  }

  const int ln15 = lane & 15, kb = (lane >> 4) << 3;
  const int m0 = (mtg << 5) + ln15;
  const int ne1 = ln15 < 8 ? 16 + ln15 : 23;   // clamp pad rows (masked on write)

  const _Float16 *b0h,*b0l,*b1h,*b1l, *a0h0,*a0l0;
  if (is0){
    const int ks0 = kg << 7;                   // kg*128 (K=1024 over 8)
    const _Float16* wbh = p.W0h + (size_t)blk*24*1024;
    const _Float16* wbl = p.W0l + (size_t)blk*24*1024;
    b0h = wbh + ln15*1024 + ks0 + kb;  b0l = wbl + ln15*1024 + ks0 + kb;
    b1h = wbh + ne1 *1024 + ks0 + kb;  b1l = wbl + ne1 *1024 + ks0 + kb;
    a0h0 = p.h0h + m0*1024 + ks0 + kb;
    a0l0 = p.h0l + m0*1024 + ks0 + kb;
  } else {
    const int ks0 = kg << 8;                   // kg*256 (K=2048 over 8)
    const _Float16* wbh = p.W1h + (size_t)blk*24*2048;
    const _Float16* wbl = p.W1l + (size_t)blk*24*2048;
    b0h = wbh + ln15*2048 + ks0 + kb;  b0l = wbl + ln15*2048 + ks0 + kb;
    b1h = wbh + ne1 *2048 + ks0 + kb;  b1l = wbl + ne1 *2048 + ks0 + kb;
    const _Float16* hh = (kg < 4) ? p.h1h : p.h0h;   // kg 0-3: Whh1.h1; 4-7: Wih1.h0
    const _Float16* hl = (kg < 4) ? p.h1l : p.h0l;
    const int aoff = ((kg & 3) << 8) + kb;
    a0h0 = hh + m0*1024 + aoff;
    a0l0 = hl + m0*1024 + aoff;
  }
  const _Float16 *a1h0 = a0h0 + (16*1024), *a1l0 = a0l0 + (16*1024);

  #pragma unroll 1
  for (int e = 0; e <= 512; ++e){
    const int cur = e & 1, prv = cur ^ 1;
    const bool active = is0 ? (e < 512) : (e >= 1);
    if (active){
      const int po = prv * BH;
      float o[16];
      if (is0) frag2<4>(a0h0+po, a0l0+po, a1h0+po, a1l0+po, b0h,b0l,b1h,b1l, o);
      else     frag2<8>(a0h0+po, a0l0+po, a1h0+po, a1l0+po, b0h,b0l,b1h,b1l, o);
      #pragma unroll
      for (int mti=0; mti<2; ++mti){
        const int mcol = (((mtg<<1)+mti)<<4) + ((lane>>4)<<2);
        #pragma unroll
        for (int r=0;r<4;++r){
          ldsA[kg][ln15][mcol+r] = o[mti*4+r];
          if (ln15 < 8) ldsA[kg][16+ln15][mcol+r] = o[8+mti*4+r];
        }
      }
    }
    __syncthreads();
    if (active && tid < 512){
      const int b = tid & 63, j = tid >> 6;
      const int col = j0 + j;
      float sr=0.f, sz=0.f, sn=0.f;
      if (is0){
        #pragma unroll
        for (int k=0;k<8;++k){ sr += ldsA[k][j][b]; sz += ldsA[k][8+j][b]; sn += ldsA[k][16+j][b]; }
        const int t = e;
        float hr = sr + ldsC[j][3], hz = sz + ldsC[8+j][3], hn = sn + ldsC[16+j][3];
        float x0 = p.x[b*1024 + t], x1 = p.x[b*1024 + 512 + t];
        float xr = fmaf(x0, ldsC[j][0],    fmaf(x1, ldsC[j][1],    ldsC[j][2]));
        float xz = fmaf(x0, ldsC[8+j][0],  fmaf(x1, ldsC[8+j][1],  ldsC[8+j][2]));
        float xn = fmaf(x0, ldsC[16+j][0], fmaf(x1, ldsC[16+j][1], ldsC[16+j][2]));
        float rg = 1.0f/(1.0f + expf(-(xr+hr)));
        float zg = 1.0f/(1.0f + expf(-(xz+hz)));
        float ng = tanhf(xn + rg*hn);
        float hold = reconf(p.h0h[prv*BH + b*1024 + col], p.h0l[prv*BH + b*1024 + col]);
        float hnew = (1.0f - zg)*ng + zg*hold;
        _Float16 hi,lo; splitf(hnew,hi,lo);
        p.h0h[cur*BH + b*1024 + col] = hi;
        p.h0l[cur*BH + b*1024 + col] = lo;
      } else {
        float xr4=0.f, xz4=0.f, xn4=0.f;
        #pragma unroll
        for (int k=0;k<4;++k){
          sr  += ldsA[k][j][b];   sz  += ldsA[k][8+j][b];   sn  += ldsA[k][16+j][b];
          xr4 += ldsA[4+k][j][b]; xz4 += ldsA[4+k][8+j][b]; xn4 += ldsA[4+k][16+j][b];
        }
        const int t = e - 1;
        float hr = sr + ldsC[j][1],  hz = sz + ldsC[8+j][1],  hn = sn + ldsC[16+j][1];
        float xr = xr4 + ldsC[j][0], xz = xz4 + ldsC[8+j][0], xn = xn4 + ldsC[16+j][0];
        float rg = 1.0f/(1.0f + expf(-(xr+hr)));
        float zg = 1.0f/(1.0f + expf(-(xz+hz)));
        float ng = tanhf(xn + rg*hn);
        float hold = reconf(p.h1h[prv*BH + b*1024 + col], p.h1l[prv*BH + b*1024 + col]);
        float hnew = (1.0f - zg)*ng + zg*hold;
        _Float16 hi,lo; splitf(hnew,hi,lo);
        p.h1h[cur*BH + b*1024 + col] = hi;
        p.h1l[cur*BH + b*1024 + col] = lo;
        p.enc_i[b*SH + t*1024 + col] = pack_pair(hnew);
      }
    }
    gbar(p.bar0, (unsigned)(e+1) << 8);
  }
}

// ---------------- decoder small GEMM: 8 rows, 2 m-groups x 4 K-slices ----------------
template<int K>
__device__ __forceinline__ void dec_mm(int tid,
    const _Float16* __restrict__ Ah, const _Float16* __restrict__ Al,
    const _Float16* __restrict__ Wh, const _Float16* __restrict__ Wl,
    float (*ldsD)[8][68])
{
  const int lane = tid & 63, wave = tid >> 6;
  const int mtg = wave & 1, kg = wave >> 1;     // kg 0..3
  const int ln15 = lane & 15, kb = (lane>>4)<<3;
  const int ks0 = kg * (K/4);
  const int ne = ln15 < 8 ? ln15 : 7;
  const _Float16* a0h = Ah + (mtg*32 + ln15)*K + ks0 + kb;
  const _Float16* a0l = Al + (mtg*32 + ln15)*K + ks0 + kb;
  const _Float16* a1h = a0h + 16*K;
  const _Float16* a1l = a0l + 16*K;
  const _Float16* wh = Wh + ne*K + ks0 + kb;
  const _Float16* wl = Wl + ne*K + ks0 + kb;
  floatx4 H0{0,0,0,0},M0{0,0,0,0},N0{0,0,0,0},H1{0,0,0,0},M1{0,0,0,0},N1{0,0,0,0};
  #pragma unroll
  for (int ks=0; ks<K/128; ++ks){
    const int off = ks<<5;
    half8 A0h = *(const half8*)(a0h+off), A0l = *(const half8*)(a0l+off);
    half8 A1h = *(const half8*)(a1h+off), A1l = *(const half8*)(a1l+off);
    half8 Bh  = *(const half8*)(wh+off),  Bl  = *(const half8*)(wl+off);
    H0 = __builtin_amdgcn_mfma_f32_16x16x32_f16(A0h,Bh,H0,0,0,0);
    M0 = __builtin_amdgcn_mfma_f32_16x16x32_f16(A0h,Bl,M0,0,0,0);
    N0 = __builtin_amdgcn_mfma_f32_16x16x32_f16(A0l,Bh,N0,0,0,0);
    H1 = __builtin_amdgcn_mfma_f32_16x16x32_f16(A1h,Bh,H1,0,0,0);
    M1 = __builtin_amdgcn_mfma_f32_16x16x32_f16(A1h,Bl,M1,0,0,0);
    N1 = __builtin_amdgcn_mfma_f32_16x16x32_f16(A1l,Bh,N1,0,0,0);
  }
  if (ln15 < 8){
    const float s = 1.f/2048.f;
    const int mc = mtg*32 + ((lane>>4)<<2);
    #pragma unroll
    for (int r=0;r<4;++r){
      ldsD[kg][ln15][mc+r]    = H0[r] + (M0[r]+N0[r])*s;
      ldsD[kg][ln15][mc+16+r] = H1[r] + (M1[r]+N1[r])*s;
    }
  }
}

// ---------------- persistent decoder ----------------
// 256 blocks x 512 thr; 64 steps x 7 phases + init + epilogue.
__global__ __launch_bounds__(512) void k_decp(P p){
  const int tid = threadIdx.x, lane = tid & 63, wave = tid >> 6;
  const int bid = blockIdx.x;
  __shared__ float sbuf[8][1032];
  __shared__ float ldsD[4][8][68];
  __shared__ float ldsL[8][68];
  __shared__ float sml[16];
  __shared__ unsigned long long sred[128];
  unsigned ph = 0;

  // ---- P0: u0 = Whh0.h0_enc + bhh0 ; u1 = Whh1.h1_enc + bhh1 ----
  {
    const bool A = bid < 128; const int blk = bid & 127;
    const _Float16* Wh = A ? p.whh0dh : p.whh1dh;
    const _Float16* Wl = A ? p.whh0dl : p.whh1dl;
    const _Float16* Ah = A ? (p.h0h + BH) : p.h1h;
    const _Float16* Al = A ? (p.h0l + BH) : p.h1l;
    dec_mm<1024>(tid, Ah, Al, Wh + (size_t)blk*8*1024, Wl + (size_t)blk*8*1024, ldsD);
    __syncthreads();
    {
      const int b = tid & 63, j = tid >> 6, col = (blk<<3) + j;
      float val = ldsD[0][j][b]+ldsD[1][j][b]+ldsD[2][j][b]+ldsD[3][j][b]
                + (A ? p.dbhh0 : p.dbhh1)[col];
      (A ? p.u0 : p.u1)[b*1024 + col] = val;
    }
    ++ph; gbar(p.bar1, ph<<8);
  }

  #pragma unroll 1
  for (int t=0; t<64; ++t){
    // ---- P1: argmax(t-1) + h0 = tanh(T0[tok] + u0) ----
    if (bid < 64){
      const int b = bid;
      unsigned long long v = 0;
      if (t > 0 && tid < 128) v = p.amax[b*128 + tid];
      if (tid < 128) sred[tid] = v;
      __syncthreads();
      for (int off=64; off>=1; off>>=1){
        if (tid < off){ unsigned long long o = sred[tid+off]; if (o > sred[tid]) sred[tid] = o; }
        __syncthreads();
      }
      const int tok = (t > 0) ? (1023 - (int)(sred[0] & 0xffffffffULL)) : 0;
      #pragma unroll
      for (int i=0;i<2;++i){
        int h = tid + (i<<9);
        float val = tanhf(reconf(p.T0h[tok*1024+h], p.T0l[tok*1024+h]) + p.u0[b*1024+h]);
        _Float16 hi,lo; splitf(val,hi,lo);
        p.dh0h[b*1024+h]=hi; p.dh0l[b*1024+h]=lo;
      }
    }
    ++ph; gbar(p.bar1, ph<<8);

    // ---- P2: A: w1x=Wih1.dh0+bih1 -> h1=tanh(w1x+u1); B: u0' = Whh0.dh0+bhh0 ----
    {
      const bool A = bid < 128; const int blk = bid & 127;
      const _Float16* Wh = A ? p.wih1dh : p.whh0dh;
      const _Float16* Wl = A ? p.wih1dl : p.whh0dl;
      dec_mm<1024>(tid, p.dh0h, p.dh0l, Wh + (size_t)blk*8*1024, Wl + (size_t)blk*8*1024, ldsD);
      __syncthreads();
      const int b = tid & 63, j = tid >> 6, col = (blk<<3) + j;
      float val = ldsD[0][j][b]+ldsD[1][j][b]+ldsD[2][j][b]+ldsD[3][j][b];
      if (A){
        float h1 = tanhf(val + p.dbih1[col] + p.u1[b*1024+col]);
        _Float16 hi,lo; splitf(h1,hi,lo);
        p.dh1h[b*1024+col]=hi; p.dh1l[b*1024+col]=lo;
        p.cath[b*2048+col]=hi; p.catl[b*2048+col]=lo;
      } else {
        p.u0[b*1024+col] = val + p.dbhh0[col];
      }
    }
    ++ph; gbar(p.bar1, ph<<8);

    // ---- P3: A: q = hq.dh1 + hqb; B: u1' = Whh1.dh1 + bhh1 ----
    {
      const bool A = bid < 128; const int blk = bid & 127;
      const _Float16* Wh = A ? p.hqh : p.whh1dh;
      const _Float16* Wl = A ? p.hql : p.whh1dl;
      dec_mm<1024>(tid, p.dh1h, p.dh1l, Wh + (size_t)blk*8*1024, Wl + (size_t)blk*8*1024, ldsD);
      __syncthreads();
      const int b = tid & 63, j = tid >> 6, col = (blk<<3) + j;
      float val = ldsD[0][j][b]+ldsD[1][j][b]+ldsD[2][j][b]+ldsD[3][j][b];
      if (A) p.q[b*1024+col]  = val + p.hqb[col];
      else   p.u1[b*1024+col] = val + p.dbhh1[col];
    }
    ++ph; gbar(p.bar1, ph<<8);

    // ---- P4: flash attention quarter (b = bid>>2, q4 = bid&3) ----
    {
      const int b = bid >> 2, q4 = bid & 3;
      const int s0 = q4 << 7;
      float qv[16];
      #pragma unroll
      for (int i=0;i<16;++i) qv[i] = p.q[b*1024 + (i<<6) + lane];
      float ov[16];
      #pragma unroll
      for (int i=0;i<16;++i) ov[i] = 0.f;
      float mrun = -3.0e38f, lrun = 0.f;
      for (int si=0; si<16; ++si){
        int s = s0 + (wave<<4) + si;
        const uint32_t* ep = p.enc_i + b*SH + s*1024 + lane;
        float ef[16]; float partial = 0.f;
        #pragma unroll
        for (int i=0;i<16;++i){
          ef[i] = recon_u32(ep[i<<6]);
          partial = fmaf(ef[i], qv[i], partial);
        }
        #pragma unroll
        for (int off=32; off; off>>=1) partial += __shfl_xor(partial, off, 64);
        if (t == 63 && lane == 0) p.sc63[b*512 + s] = partial;
        float mnew = fmaxf(mrun, partial);
        float fac = __expf(mrun - mnew);
        float w   = __expf(partial - mnew);
        lrun = fmaf(lrun, fac, w);
        #pragma unroll
        for (int i=0;i<16;++i) ov[i] = fmaf(ov[i], fac, w*ef[i]);
        mrun = mnew;
      }
      #pragma unroll
      for (int i=0;i<16;++i) sbuf[wave][(i<<6)+lane] = ov[i];
      if (lane == 0){ sml[wave] = mrun; sml[8+wave] = lrun; }
      __syncthreads();
      float M = sml[0];
      #pragma unroll
      for (int w=1;w<8;++w) M = fmaxf(M, sml[w]);
      float fw[8], L = 0.f;
      #pragma unroll
      for (int w=0;w<8;++w){ fw[w] = __expf(sml[w]-M); L += fw[w]*sml[8+w]; }
      if (tid == 0){ p.attp_ml[(b*4+q4)*2] = M; p.attp_ml[(b*4+q4)*2+1] = L; }
      #pragma unroll
      for (int i=0;i<2;++i){
        int h = tid + (i<<9);
        float o = 0.f;
        #pragma unroll
        for (int w=0;w<8;++w) o += fw[w]*sbuf[w][h];
        p.attp_o[(b*4+q4)*1024 + h] = o;
      }
    }
    ++ph; gbar(p.bar1, ph<<8);

    // ---- P5: combine quarters -> att into cat[:,1024:]; t=63: attn output ----
    if (bid < 64){
      const int b = bid;
      float m0=p.attp_ml[b*8+0], l0=p.attp_ml[b*8+1];
      float m1=p.attp_ml[b*8+2], l1=p.attp_ml[b*8+3];
      float m2=p.attp_ml[b*8+4], l2=p.attp_ml[b*8+5];
      float m3=p.attp_ml[b*8+6], l3=p.attp_ml[b*8+7];
      float M = fmaxf(fmaxf(m0,m1), fmaxf(m2,m3));
      float f0=expf(m0-M), f1=expf(m1-M), f2=expf(m2-M), f3=expf(m3-M);
      float invL = 1.0f/(f0*l0 + f1*l1 + f2*l2 + f3*l3);
      #pragma unroll
      for (int i=0;i<2;++i){
        int h = tid + (i<<9);
        float o = (f0*p.attp_o[(b*4+0)*1024+h] + f1*p.attp_o[(b*4+1)*1024+h]
                 + f2*p.attp_o[(b*4+2)*1024+h] + f3*p.attp_o[(b*4+3)*1024+h]) * invL;
        _Float16 hi,lo; splitf(o,hi,lo);
        p.cath[b*2048 + 1024 + h] = hi; p.catl[b*2048 + 1024 + h] = lo;
      }
      if (t == 63){
        int s = tid;
        p.dout[OFF_ATTN + b*512 + s] = expf(p.sc63[b*512+s] - M) * invL;
      }
    }
    ++ph; gbar(p.bar1, ph<<8);

    // ---- P6: c = comb_W.[h1|att] + comb_b ----
    if (bid < 128){
      dec_mm<2048>(tid, p.cath, p.catl,
                   p.combh + (size_t)bid*8*2048, p.combl + (size_t)bid*8*2048, ldsD);
      __syncthreads();
      const int b = tid & 63, j = tid >> 6, col = (bid<<3) + j;
      float val = ldsD[0][j][b]+ldsD[1][j][b]+ldsD[2][j][b]+ldsD[3][j][b] + p.combb[col];
      _Float16 hi,lo; splitf(val,hi,lo);
      p.ch[b*1024+col]=hi; p.cl[b*1024+col]=lo;
    }
    ++ph; gbar(p.bar1, ph<<8);

    // ---- P7: logits = fc.c + fc_b -> dout + argmax partials ----
    if (bid < 128){
      dec_mm<1024>(tid, p.ch, p.cl,
                   p.fch + (size_t)bid*8*1024, p.fcl + (size_t)bid*8*1024, ldsD);
      __syncthreads();
      const int b = tid & 63, j = tid >> 6, col = (bid<<3) + j;
      float val = ldsD[0][j][b]+ldsD[1][j][b]+ldsD[2][j][b]+ldsD[3][j][b] + p.fcb[col];
      p.dout[b*65536 + t*1024 + col] = val;
      ldsL[j][b] = val;
      __syncthreads();
      if (tid < 64){
        int b2 = tid; float best = -3.0e38f; int bi = 0;
        #pragma unroll
        for (int jj=0; jj<8; ++jj){
          float v = ldsL[jj][b2];
          if (v > best){ best = v; bi = jj; }
        }
        unsigned long long pk = ((unsigned long long)ordf(best) << 32)
                              | (unsigned)(1023 - ((bid<<3) + bi));
        p.amax[b2*128 + bid] = pk;
      }
    }
    ++ph; gbar(p.bar1, ph<<8);
  }

  // ---- final hidden output [2][B][H] ----
  {
    int idx = bid*512 + tid;            // 131072 exactly
    int i = idx & 65535;
    float v = (idx >> 16) ? reconf(p.dh1h[i], p.dh1l[i]) : reconf(p.dh0h[i], p.dh0l[i]);
    p.dout[OFF_HID + idx] = v;
  }
}

// ---------------- host ----------------
extern "C" void kernel_launch(void* const* d_in, const int* in_sizes, int n_in,
                              void* d_out, int out_size, void* d_ws, size_t ws_size,
                              hipStream_t stream)
{
  (void)in_sizes; (void)n_in; (void)out_size;
  P p;
  p.x     = (const float*)d_in[0];  p.emb   = (const float*)d_in[1];
  p.eWih0 = (const float*)d_in[2];  p.eWhh0 = (const float*)d_in[3];
  p.ebih0 = (const float*)d_in[4];  p.ebhh0 = (const float*)d_in[5];
  p.dWih0 = (const float*)d_in[6];  p.dWhh0 = (const float*)d_in[7];
  p.dbih0 = (const float*)d_in[8];  p.dbhh0 = (const float*)d_in[9];
  p.eWih1 = (const float*)d_in[10]; p.eWhh1 = (const float*)d_in[11];
  p.ebih1 = (const float*)d_in[12]; p.ebhh1 = (const float*)d_in[13];
  p.dWih1 = (const float*)d_in[14]; p.dWhh1 = (const float*)d_in[15];
  p.dbih1 = (const float*)d_in[16]; p.dbhh1 = (const float*)d_in[17];
  p.hqW   = (const float*)d_in[18]; p.hqb   = (const float*)d_in[19];
  p.combW = (const float*)d_in[20]; p.combb = (const float*)d_in[21];
  p.fcW   = (const float*)d_in[22]; p.fcb   = (const float*)d_in[23];
  p.dout  = (float*)d_out;

  char* base = (char*)d_ws; size_t off = 0;
  auto alloc = [&](size_t bytes)->char*{
    char* r = base + off; off = (off + bytes + 255) & ~(size_t)255; return r;
  };
  p.enc_i = (uint32_t*)alloc(33554432ULL*4);
  p.W0h = (_Float16*)alloc(3145728ULL*2);  p.W0l = (_Float16*)alloc(3145728ULL*2);
  p.W1h = (_Float16*)alloc(6291456ULL*2);  p.W1l = (_Float16*)alloc(6291456ULL*2);
  p.embh = (_Float16*)alloc(1048576ULL*2); p.embl = (_Float16*)alloc(1048576ULL*2);
  p.T0h  = (_Float16*)alloc(1048576ULL*2); p.T0l  = (_Float16*)alloc(1048576ULL*2);
  p.wih0dh=(_Float16*)alloc(1048576ULL*2); p.wih0dl=(_Float16*)alloc(1048576ULL*2);
  p.wih1dh=(_Float16*)alloc(1048576ULL*2); p.wih1dl=(_Float16*)alloc(1048576ULL*2);
  p.whh0dh=(_Float16*)alloc(1048576ULL*2); p.whh0dl=(_Float16*)alloc(1048576ULL*2);
  p.whh1dh=(_Float16*)alloc(1048576ULL*2); p.whh1dl=(_Float16*)alloc(1048576ULL*2);
  p.hqh  = (_Float16*)alloc(1048576ULL*2); p.hql  = (_Float16*)alloc(1048576ULL*2);
  p.combh= (_Float16*)alloc(2097152ULL*2); p.combl= (_Float16*)alloc(2097152ULL*2);
  p.fch  = (_Float16*)alloc(1048576ULL*2); p.fcl  = (_Float16*)alloc(1048576ULL*2);
  p.h0h  = (_Float16*)alloc(131072ULL*2);  p.h0l  = (_Float16*)alloc(131072ULL*2);
  p.h1h  = (_Float16*)alloc(131072ULL*2);  p.h1l  = (_Float16*)alloc(131072ULL*2);
  p.dh0h = (_Float16*)alloc(65536ULL*2);   p.dh0l = (_Float16*)alloc(65536ULL*2);
  p.dh1h = (_Float16*)alloc(65536ULL*2);   p.dh1l = (_Float16*)alloc(65536ULL*2);
  p.cath = (_Float16*)alloc(131072ULL*2);  p.catl = (_Float16*)alloc(131072ULL*2);
  p.ch   = (_Float16*)alloc(65536ULL*2);   p.cl   = (_Float16*)alloc(65536ULL*2);
  p.u0   = (float*)alloc(65536ULL*4);      p.u1   = (float*)alloc(65536ULL*4);
  p.q    = (float*)alloc(65536ULL*4);
  p.attp_o  = (float*)alloc(262144ULL*4);
  p.attp_ml = (float*)alloc(512ULL*4);
  p.sc63    = (float*)alloc(32768ULL*4);
  p.amax    = (unsigned long long*)alloc(8192ULL*8);
  {
    unsigned* bars = (unsigned*)alloc(256);
    p.bar0 = bars; p.bar1 = bars + 16;
  }
  if (off > ws_size) return;

  k_splitall<<<4096,256,0,stream>>>(p);
  k_rw0<<<4096,256,0,stream>>>(p);
  k_rw1<<<4096,256,0,stream>>>(p);
  k_zero<<<256,256,0,stream>>>(p);
  k_t0<<<1024,256,0,stream>>>(p);
  k_encp<<<256,1024,0,stream>>>(p);
  k_decp<<<256,512,0,stream>>>(p);
}

// Round 3
// 40063.187 us; speedup vs baseline: 1.1539x; 1.1539x over previous
//
#include <hip/hip_runtime.h>
#include <stdint.h>

// ---------------------------------------------------------------------------
// Round 3: persistent kernels with LDS-resident weights + system-scope stores
// and an invalidate-only grid barrier (no wbl2, no stale spins).
// Precision: fp16 hi/lo split GEMMs (3 MFMA, fp32 accum); enc_outs for
// attention stored as plain f16 (safe: softmax/argmax analysis in journal).
// ---------------------------------------------------------------------------

#define BB 64
#define SS 512
#define TT 64
#define HH 1024
#define VV 1024
#define BH 65536   // B*H
#define SH 524288  // S*H
#define OFF_HID  4194304           // B*T*V
#define OFF_ATTN 4325376           // + L*B*H

#define ENC_LDS 158304
#define DEC_LDS 137472

typedef _Float16 half8  __attribute__((ext_vector_type(8)));
typedef float    floatx4 __attribute__((ext_vector_type(4)));

#define MFMA16(a,b,c) __builtin_amdgcn_mfma_f32_16x16x32_f16(a,b,c,0,0,0)

struct P {
  const float *x, *emb;
  const float *eWih0, *eWhh0, *ebih0, *ebhh0;
  const float *dWih0, *dWhh0, *dbih0, *dbhh0;
  const float *eWih1, *eWhh1, *ebih1, *ebhh1;
  const float *dWih1, *dWhh1, *dbih1, *dbhh1;
  const float *hqW, *hqb, *combW, *combb, *fcW, *fcb;
  uint32_t* enc_att;               // [B][S][H] f16, 2 per u32
  _Float16 *embh,*embl,*T0h,*T0l;  // T0 = emb @ dWih0^T + dbih0  [V][H] pairs
  _Float16 *wih0dh,*wih0dl;
  _Float16 *h0h,*h0l,*h1h,*h1l;    // [2][B*H] parity-double-buffered enc states
  _Float16 *dh0h,*dh0l,*dh1h,*dh1l;// decoder states [B*H]
  _Float16 *cath,*catl;            // [B][2048] = [h1 | att] pairs
  _Float16 *ch,*cl;                // comb output pairs [B*H]
  float *u0,*u1,*q;                // fp32 [B*H]
  float *attp_o;                   // [B][4][H]
  float *attp_ml;                  // [B][4][2]
  float *sc63;                     // [B][S] raw scores at t=63
  unsigned long long* amax;        // [B][256] argmax partials
  unsigned *bar0, *bar1;           // 4-way-spread grid-barrier counters
  float* dout;
};

// ---------------- helpers ----------------
__device__ __forceinline__ void splitf(float x, _Float16& hi, _Float16& lo){
  _Float16 h = (_Float16)x; hi = h;
  lo = (_Float16)((x - (float)h) * 2048.0f);
}
__device__ __forceinline__ float reconf(_Float16 hi, _Float16 lo){
  return fmaf((float)lo, 1.0f/2048.0f, (float)hi);
}
__device__ __forceinline__ unsigned ordf(float f){
  unsigned u = __float_as_uint(f);
  return (u & 0x80000000u) ? ~u : (u | 0x80000000u);
}
__device__ __forceinline__ void pack2(float v0, float v1, uint32_t& ph, uint32_t& pl){
  _Float16 h0,l0,h1,l1; splitf(v0,h0,l0); splitf(v1,h1,l1);
  ph = (uint32_t)__builtin_bit_cast(unsigned short,h0)
     | ((uint32_t)__builtin_bit_cast(unsigned short,h1) << 16);
  pl = (uint32_t)__builtin_bit_cast(unsigned short,l0)
     | ((uint32_t)__builtin_bit_cast(unsigned short,l1) << 16);
}
// system-scope stores: bypass L2 (coherent at L3) so the barrier needs no wbl2
__device__ __forceinline__ void st_u32(uint32_t* p2, uint32_t v){
  __hip_atomic_store(p2, v, __ATOMIC_RELAXED, __HIP_MEMORY_SCOPE_SYSTEM);
}
__device__ __forceinline__ void st_f32(float* p2, float v){
  __hip_atomic_store(p2, v, __ATOMIC_RELAXED, __HIP_MEMORY_SCOPE_SYSTEM);
}
__device__ __forceinline__ void st_u64(unsigned long long* p2, unsigned long long v){
  __hip_atomic_store(p2, v, __ATOMIC_RELAXED, __HIP_MEMORY_SCOPE_SYSTEM);
}

// Grid barrier: 4 spread counters, SYSTEM-scope add + poll (always coherent),
// acquire-only fence (L1/L2 invalidate, no writeback — all stores were system).
__device__ __forceinline__ void gbar(unsigned* c, unsigned target){
  __syncthreads();                       // drains vmcnt: system stores complete
  if (threadIdx.x == 0){
    __hip_atomic_fetch_add(c + (blockIdx.x & 3)*64, 1u,
                           __ATOMIC_RELEASE, __HIP_MEMORY_SCOPE_SYSTEM);
    unsigned s;
    do {
      __builtin_amdgcn_s_sleep(2);
      s = __hip_atomic_load(c,       __ATOMIC_RELAXED, __HIP_MEMORY_SCOPE_SYSTEM)
        + __hip_atomic_load(c + 64,  __ATOMIC_RELAXED, __HIP_MEMORY_SCOPE_SYSTEM)
        + __hip_atomic_load(c + 128, __ATOMIC_RELAXED, __HIP_MEMORY_SCOPE_SYSTEM)
        + __hip_atomic_load(c + 192, __ATOMIC_RELAXED, __HIP_MEMORY_SCOPE_SYSTEM);
    } while (s < target);
  }
  __syncthreads();
  __builtin_amdgcn_fence(__ATOMIC_ACQUIRE, "agent");   // inv L1+L2, no wbl2
}

// ---------------- split-precision GEMM core (k_t0 only) ----------------
template<int NT, int KH, bool SPLIT>
__device__ __forceinline__ void gemm_core(
    const _Float16* __restrict__ Ah0, const _Float16* __restrict__ Al0,
    const _Float16* __restrict__ Ah1, const _Float16* __restrict__ Al1,
    int sA,
    const _Float16* __restrict__ Wh, const _Float16* __restrict__ Wl,
    int nrows, _Float16* ldsW, float* accOut)
{
  const int tid = threadIdx.x, lane = tid & 63, wave = tid >> 6;
  const int mA = (wave<<4) + (lane & 15);
  const int kb = ((lane>>4) << 3);
  const int wstride = KH << 10;
  floatx4 aH[NT], aM1[NT], aM2[NT];
  int ne[NT];
  const _Float16* bh_base[NT];
  const _Float16* bl_base[NT];
  #pragma unroll
  for (int nt=0; nt<NT; ++nt){
    int nn = (lane & 15) + (nt<<4);
    ne[nt] = nn < nrows ? nn : nrows - 1;
    bh_base[nt] = ldsW + ne[nt]*1032 + kb;
    aH[nt]  = floatx4{0.f,0.f,0.f,0.f};
    aM1[nt] = floatx4{0.f,0.f,0.f,0.f};
    aM2[nt] = floatx4{0.f,0.f,0.f,0.f};
  }
  #pragma unroll
  for (int kh=0; kh<KH; ++kh){
    __syncthreads();
    const int iters = (nrows*128 + 255) >> 8;
    for (int it=0; it<iters; ++it){
      int idx = tid + (it<<8);
      int row = idx >> 7, col = (idx & 127) << 3;
      if (row < nrows)
        *(half8*)(ldsW + row*1032 + col) =
            *(const half8*)(Wh + row*wstride + (kh<<10) + col);
    }
    __syncthreads();
    const _Float16* ah_p = ((KH==2 && kh==1) ? Ah1 : Ah0) + mA*sA + kb;
    const _Float16* al_p = ((KH==2 && kh==1) ? Al1 : Al0) + mA*sA + kb;
    #pragma unroll
    for (int nt=0; nt<NT; ++nt) bl_base[nt] = Wl + ne[nt]*wstride + (kh<<10) + kb;
    #pragma unroll 4
    for (int ks=0; ks<32; ++ks){
      half8 ah = *(const half8*)(ah_p + (ks<<5));
      half8 al = *(const half8*)(al_p + (ks<<5));
      #pragma unroll
      for (int nt=0; nt<NT; ++nt){
        half8 bh = *(const half8*)(bh_base[nt] + (ks<<5));
        half8 bl = *(const half8*)(bl_base[nt] + (ks<<5));
        aH[nt]  = MFMA16(ah, bh, aH[nt]);
        aM1[nt] = MFMA16(ah, bl, aM1[nt]);
        aM2[nt] = MFMA16(al, bh, aM2[nt]);
      }
    }
  }
  #pragma unroll
  for (int nt=0; nt<NT; ++nt)
    #pragma unroll
    for (int r=0;r<4;++r)
      accOut[nt*4 + r] = aH[nt][r] + (aM1[nt][r] + aM2[nt][r]) * (1.f/2048.f);
}

// ---------------- prologue kernels ----------------
__global__ __launch_bounds__(256) void k_split(const float* __restrict__ src,
                                               _Float16* dh, _Float16* dl, int n){
  for (int i = blockIdx.x*256 + threadIdx.x; i < n; i += gridDim.x*256){
    _Float16 hi,lo; splitf(src[i],hi,lo); dh[i]=hi; dl[i]=lo;
  }
}
__global__ __launch_bounds__(256) void k_zero(P p){
  int i = blockIdx.x*256 + threadIdx.x;   // grid 256 -> 65536 threads
  p.h1h[i] = (_Float16)0.f; p.h1l[i] = (_Float16)0.f;           // h1 parity 0
  p.h0h[BH + i] = (_Float16)0.f; p.h0l[BH + i] = (_Float16)0.f; // h0 parity 1
  if (i < 512) p.bar0[i] = 0u;            // both barrier sets (bar1 = bar0+256)
}
// T0[v][j] = emb[v] . dWih0[j] + dbih0[j]
__global__ __launch_bounds__(256) void k_t0(P p){
  __shared__ _Float16 ldsW[16*1032];
  const int ns = blockIdx.x & 63, mc = blockIdx.x >> 6;
  float acc[4];
  gemm_core<1,1,false>(p.embh + mc*65536, p.embl + mc*65536, nullptr, nullptr, 1024,
                       p.wih0dh + ns*16*1024, p.wih0dl + ns*16*1024, 16, ldsW, acc);
  const int lane = threadIdx.x & 63, wave = threadIdx.x >> 6;
  const int n = lane & 15, col = (ns<<4) + n;
  const float bv = p.dbih0[col];
  #pragma unroll
  for (int r=0;r<4;++r){
    int v = mc*64 + (wave<<4) + ((lane>>4)<<2) + r;
    _Float16 hi,lo; splitf(acc[r] + bv, hi, lo);
    p.T0h[v*1024 + col] = hi; p.T0l[v*1024 + col] = lo;
  }
}

// ---------------- persistent encoder ----------------
// 256 blocks x 512 thr; block owns 4 output cols j of BOTH layers.
// LDS: W0 (12x1032 pairs), W1 (12x2056 pairs), reduction ldsA[36][68], consts.
// waves 0-3: layer0 m-tiles; waves 4-7: layer1 m-tiles (two K-halves separate).
__global__ __launch_bounds__(512,1) void k_encp(P p){
  extern __shared__ char smem[];
  _Float16* W0h = (_Float16*)smem;       // 12*1032
  _Float16* W0l = W0h + 12384;
  _Float16* W1h = W0l + 12384;           // 12*2056
  _Float16* W1l = W1h + 24672;
  float* ldsA = (float*)(smem + 148224); // [36][68]
  float* ldsC = ldsA + 2448;             // [12][6]
  const int tid = threadIdx.x, lane = tid & 63, wave = tid >> 6;
  const int bid = blockIdx.x, j0 = bid << 2;

  for (int idx=tid; idx<12*1024; idx+=512){
    int r=idx>>10, k=idx&1023;
    int grow=(r>>2)*1024 + j0 + (r&3);
    _Float16 hi,lo; splitf(p.eWhh0[grow*1024+k],hi,lo);
    W0h[r*1032+k]=hi; W0l[r*1032+k]=lo;
  }
  for (int idx=tid; idx<12*2048; idx+=512){
    int r=idx>>11, k=idx&2047;
    int grow=(r>>2)*1024 + j0 + (r&3);
    float v = (k<1024)? p.eWhh1[grow*1024+k] : p.eWih1[grow*1024+(k-1024)];
    _Float16 hi,lo; splitf(v,hi,lo);
    W1h[r*2056+k]=hi; W1l[r*2056+k]=lo;
  }
  if (tid<12){
    int grow=(tid>>2)*1024 + j0 + (tid&3);
    ldsC[tid*6+0]=p.eWih0[grow*2+0]; ldsC[tid*6+1]=p.eWih0[grow*2+1];
    ldsC[tid*6+2]=p.ebih0[grow];     ldsC[tid*6+3]=p.ebhh0[grow];
    ldsC[tid*6+4]=p.ebih1[grow];     ldsC[tid*6+5]=p.ebhh1[grow];
  }
  __syncthreads();

  const int ln15 = lane & 15, kb = (lane >> 4) << 3;
  const bool isl1 = wave >= 4;
  const int mt = wave & 3;
  const int brow = (ln15 < 12) ? ln15 : 11;
  const int mrow = (mt<<4) + ln15;
  const int msub = (mt<<4) + ((lane>>4)<<2);

  #pragma unroll 1
  for (int e=0; e<=512; ++e){
    const int cur=e&1, prv=cur^1;
    if (!isl1){
      if (e < 512){
        const _Float16* ah = p.h0h + prv*BH + mrow*1024 + kb;
        const _Float16* al = p.h0l + prv*BH + mrow*1024 + kb;
        const _Float16* bh = W0h + brow*1032 + kb;
        const _Float16* bl = W0l + brow*1032 + kb;
        floatx4 H{0,0,0,0},M{0,0,0,0},N{0,0,0,0};
        #pragma unroll 8
        for (int ks=0;ks<32;++ks){
          int off=ks<<5;
          half8 A=*(const half8*)(ah+off), Alo=*(const half8*)(al+off);
          half8 B=*(const half8*)(bh+off), Blo=*(const half8*)(bl+off);
          H=MFMA16(A,B,H); M=MFMA16(A,Blo,M); N=MFMA16(Alo,B,N);
        }
        if (ln15<12){
          #pragma unroll
          for (int r=0;r<4;++r)
            ldsA[ln15*68 + msub + r] = H[r] + (M[r]+N[r])*(1.f/2048.f);
        }
      }
    } else {
      if (e >= 1){
        const _Float16* a1h = p.h1h + prv*BH + mrow*1024 + kb;
        const _Float16* a1l = p.h1l + prv*BH + mrow*1024 + kb;
        const _Float16* a0h = p.h0h + prv*BH + mrow*1024 + kb;
        const _Float16* a0l = p.h0l + prv*BH + mrow*1024 + kb;
        const _Float16* bh = W1h + brow*2056 + kb;
        const _Float16* bl = W1l + brow*2056 + kb;
        floatx4 H1{0,0,0,0},M1{0,0,0,0},N1{0,0,0,0};
        floatx4 H2{0,0,0,0},M2{0,0,0,0},N2{0,0,0,0};
        #pragma unroll 8
        for (int ks=0;ks<32;++ks){
          int off=ks<<5;
          half8 A=*(const half8*)(a1h+off), Alo=*(const half8*)(a1l+off);
          half8 B=*(const half8*)(bh+off), Blo=*(const half8*)(bl+off);
          H1=MFMA16(A,B,H1); M1=MFMA16(A,Blo,M1); N1=MFMA16(Alo,B,N1);
        }
        #pragma unroll 8
        for (int ks=0;ks<32;++ks){
          int off=ks<<5;
          half8 A=*(const half8*)(a0h+off), Alo=*(const half8*)(a0l+off);
          half8 B=*(const half8*)(bh+1024+off), Blo=*(const half8*)(bl+1024+off);
          H2=MFMA16(A,B,H2); M2=MFMA16(A,Blo,M2); N2=MFMA16(Alo,B,N2);
        }
        if (ln15<12){
          #pragma unroll
          for (int r=0;r<4;++r){
            ldsA[(12+ln15)*68 + msub + r] = H1[r] + (M1[r]+N1[r])*(1.f/2048.f);
            ldsA[(24+ln15)*68 + msub + r] = H2[r] + (M2[r]+N2[r])*(1.f/2048.f);
          }
        }
      }
    }
    __syncthreads();
    if (tid < 256){
      const bool l1t = tid >= 128;
      const int b = tid & 63, jp = (tid>>6) & 1;
      const int c0 = j0 + (jp<<1);
      if (!l1t && e < 512){
        const float x0 = p.x[b*1024+e], x1 = p.x[b*1024+512+e];
        float nv[2];
        #pragma unroll
        for (int d=0; d<2; ++d){
          int jj=(jp<<1)+d, r0=jj, r1=4+jj, r2=8+jj;
          float hr = ldsA[r0*68+b] + ldsC[r0*6+3];
          float hz = ldsA[r1*68+b] + ldsC[r1*6+3];
          float hn = ldsA[r2*68+b] + ldsC[r2*6+3];
          float xr = fmaf(x0, ldsC[r0*6+0], fmaf(x1, ldsC[r0*6+1], ldsC[r0*6+2]));
          float xz = fmaf(x0, ldsC[r1*6+0], fmaf(x1, ldsC[r1*6+1], ldsC[r1*6+2]));
          float xn = fmaf(x0, ldsC[r2*6+0], fmaf(x1, ldsC[r2*6+1], ldsC[r2*6+2]));
          float rg = 1.0f/(1.0f + expf(-(xr+hr)));
          float zg = 1.0f/(1.0f + expf(-(xz+hz)));
          float ng = tanhf(xn + rg*hn);
          float hold = reconf(p.h0h[prv*BH + b*1024 + c0+d], p.h0l[prv*BH + b*1024 + c0+d]);
          nv[d] = (1.0f - zg)*ng + zg*hold;
        }
        uint32_t ph_,pl_; pack2(nv[0],nv[1],ph_,pl_);
        st_u32((uint32_t*)(p.h0h + cur*BH) + ((b*1024+c0)>>1), ph_);
        st_u32((uint32_t*)(p.h0l + cur*BH) + ((b*1024+c0)>>1), pl_);
      } else if (l1t && e >= 1){
        const int t = e-1;
        float nv[2];
        #pragma unroll
        for (int d=0; d<2; ++d){
          int jj=(jp<<1)+d, r0=jj, r1=4+jj, r2=8+jj;
          float hr = ldsA[(12+r0)*68+b] + ldsC[r0*6+5];
          float hz = ldsA[(12+r1)*68+b] + ldsC[r1*6+5];
          float hn = ldsA[(12+r2)*68+b] + ldsC[r2*6+5];
          float xr = ldsA[(24+r0)*68+b] + ldsC[r0*6+4];
          float xz = ldsA[(24+r1)*68+b] + ldsC[r1*6+4];
          float xn = ldsA[(24+r2)*68+b] + ldsC[r2*6+4];
          float rg = 1.0f/(1.0f + expf(-(xr+hr)));
          float zg = 1.0f/(1.0f + expf(-(xz+hz)));
          float ng = tanhf(xn + rg*hn);
          float hold = reconf(p.h1h[prv*BH + b*1024 + c0+d], p.h1l[prv*BH + b*1024 + c0+d]);
          nv[d] = (1.0f - zg)*ng + zg*hold;
        }
        uint32_t ph_,pl_; pack2(nv[0],nv[1],ph_,pl_);
        st_u32((uint32_t*)(p.h1h + cur*BH) + ((b*1024+c0)>>1), ph_);
        st_u32((uint32_t*)(p.h1l + cur*BH) + ((b*1024+c0)>>1), pl_);
        _Float16 e0=(_Float16)nv[0], e1=(_Float16)nv[1];
        uint32_t pe = (uint32_t)__builtin_bit_cast(unsigned short,e0)
                    | ((uint32_t)__builtin_bit_cast(unsigned short,e1) << 16);
        st_u32(p.enc_att + (((size_t)b*SH + t*1024 + c0)>>1), pe);
      }
    }
    gbar(p.bar0, (unsigned)(e+1) << 8);
  }
}

// ---------------- decoder GEMM helpers (weights in LDS) ----------------
// DUAL: wave = (mt, sel); sel picks (A,W) pair, full K=1024. out ldsD[sel][4][68].
__device__ __forceinline__ void dmm_dual(int lane, int wave,
    const _Float16* A0h, const _Float16* A0l,
    const _Float16* A1h, const _Float16* A1l,
    const _Float16* W0h_, const _Float16* W0l_,
    const _Float16* W1h_, const _Float16* W1l_,
    float* ldsD)
{
  const int mt = wave>>1, sel = wave&1;
  const int ln15 = lane&15, kb = (lane>>4)<<3, n = ln15&3;
  const _Float16* ah = (sel? A1h:A0h) + ((mt<<4)+ln15)*1024 + kb;
  const _Float16* al = (sel? A1l:A0l) + ((mt<<4)+ln15)*1024 + kb;
  const _Float16* bh = (sel? W1h_:W0h_) + n*1032 + kb;
  const _Float16* bl = (sel? W1l_:W0l_) + n*1032 + kb;
  floatx4 H{0,0,0,0},M{0,0,0,0},N{0,0,0,0};
  #pragma unroll 8
  for (int ks=0;ks<32;++ks){
    int off=ks<<5;
    half8 A=*(const half8*)(ah+off), Alo=*(const half8*)(al+off);
    half8 B=*(const half8*)(bh+off), Blo=*(const half8*)(bl+off);
    H=MFMA16(A,B,H); M=MFMA16(A,Blo,M); N=MFMA16(Alo,B,N);
  }
  if (ln15 < 4){
    #pragma unroll
    for (int r=0;r<4;++r)
      ldsD[sel*272 + n*68 + (mt<<4)+((lane>>4)<<2)+r] = H[r]+(M[r]+N[r])*(1.f/2048.f);
  }
}
// SPLITK: wave = (mt, kg); one matrix, K split in halves. out ldsD[kg][4][68].
template<int K>
__device__ __forceinline__ void dmm_sk(int lane, int wave,
    const _Float16* Ah, const _Float16* Al,
    const _Float16* Wh_, const _Float16* Wl_,
    float* ldsD)
{
  const int mt = wave>>1, kg = wave&1;
  const int ln15 = lane&15, kb = (lane>>4)<<3, n = ln15&3;
  const int k0 = kg*(K/2);
  const _Float16* ah = Ah + ((mt<<4)+ln15)*K + k0 + kb;
  const _Float16* al = Al + ((mt<<4)+ln15)*K + k0 + kb;
  const _Float16* bh = Wh_ + n*(K+8) + k0 + kb;
  const _Float16* bl = Wl_ + n*(K+8) + k0 + kb;
  floatx4 H{0,0,0,0},M{0,0,0,0},N{0,0,0,0};
  #pragma unroll 8
  for (int ks=0;ks<K/64;++ks){
    int off=ks<<5;
    half8 A=*(const half8*)(ah+off), Alo=*(const half8*)(al+off);
    half8 B=*(const half8*)(bh+off), Blo=*(const half8*)(bl+off);
    H=MFMA16(A,B,H); M=MFMA16(A,Blo,M); N=MFMA16(Alo,B,N);
  }
  if (ln15 < 4){
    #pragma unroll
    for (int r=0;r<4;++r)
      ldsD[kg*272 + n*68 + (mt<<4)+((lane>>4)<<2)+r] = H[r]+(M[r]+N[r])*(1.f/2048.f);
  }
}

// ---------------- persistent decoder ----------------
// 256 blocks x 512 thr; block owns cols j0..j0+3 of all 6 decoder matrices (LDS).
__global__ __launch_bounds__(512,1) void k_decp(P p){
  extern __shared__ char smem[];
  _Float16* wih1h=(_Float16*)smem;      _Float16* wih1l=wih1h+4128;
  _Float16* whh0h=wih1l+4128;           _Float16* whh0l=whh0h+4128;
  _Float16* hqh2 =whh0l+4128;           _Float16* hql2 =hqh2+4128;
  _Float16* whh1h=hql2+4128;            _Float16* whh1l=whh1h+4128;
  _Float16* fch2 =whh1l+4128;           _Float16* fcl2 =fch2+4128;
  _Float16* combh2=fcl2+4128;           _Float16* combl2=combh2+8224;
  float* sbufA=(float*)(smem+115456);   // [4][1032]
  float* ldsD =(float*)(smem+131968);   // [2][4][68]
  float* ldsL =(float*)(smem+134144);   // [4][68]
  float* sml  =(float*)(smem+135232);   // [16]
  float* cb   =(float*)(smem+135296);   // [6][4]
  unsigned long long* sred=(unsigned long long*)(smem+135424); // [256]

  const int tid=threadIdx.x, lane=tid&63, wave=tid>>6;
  const int bid=blockIdx.x, j0=bid<<2;

  { const float* mats[5]={p.dWih1,p.dWhh0,p.hqW,p.dWhh1,p.fcW};
    _Float16* mh[5]={wih1h,whh0h,hqh2,whh1h,fch2};
    _Float16* ml[5]={wih1l,whh0l,hql2,whh1l,fcl2};
    #pragma unroll 1
    for (int m5=0;m5<5;++m5)
      for (int idx=tid; idx<4096; idx+=512){
        int r=idx>>10,k=idx&1023;
        _Float16 hi,lo; splitf(mats[m5][(j0+r)*1024+k],hi,lo);
        mh[m5][r*1032+k]=hi; ml[m5][r*1032+k]=lo;
      }
    for (int idx=tid; idx<8192; idx+=512){
      int r=idx>>11,k=idx&2047;
      _Float16 hi,lo; splitf(p.combW[(j0+r)*2048+k],hi,lo);
      combh2[r*2056+k]=hi; combl2[r*2056+k]=lo;
    }
    if (tid<4){
      cb[0*4+tid]=p.dbih1[j0+tid]; cb[1*4+tid]=p.dbhh0[j0+tid];
      cb[2*4+tid]=p.hqb[j0+tid];   cb[3*4+tid]=p.dbhh1[j0+tid];
      cb[4*4+tid]=p.combb[j0+tid]; cb[5*4+tid]=p.fcb[j0+tid];
    }
  }
  __syncthreads();
  unsigned phx = 0;

  // ---- P0: u0 = Whh0.h0_enc + bhh0 ; u1 = Whh1.h1_enc + bhh1 ----
  dmm_dual(lane,wave, p.h0h+BH,p.h0l+BH, p.h1h,p.h1l,
           whh0h,whh0l, whh1h,whh1l, ldsD);
  __syncthreads();
  if (tid<256){
    int b=tid&63, j=tid>>6, col=j0+j;
    st_f32(p.u0 + b*1024+col, ldsD[j*68+b]     + cb[1*4+j]);
    st_f32(p.u1 + b*1024+col, ldsD[272+j*68+b] + cb[3*4+j]);
  }
  ++phx; gbar(p.bar1, phx<<8);

  #pragma unroll 1
  for (int t=0; t<64; ++t){
    // ---- P1: argmax(t-1) + h0 = tanh(T0[tok] + u0) ----
    if (bid < 64){
      const int b = bid;
      if (tid<256){
        unsigned long long v=0;
        if (t>0) v = p.amax[b*256+tid];
        sred[tid]=v;
      }
      __syncthreads();
      for (int o=128;o>=1;o>>=1){
        if (tid<o){ unsigned long long x=sred[tid+o]; if (x>sred[tid]) sred[tid]=x; }
        __syncthreads();
      }
      const int tok = (t>0)? (1023 - (int)(sred[0]&0xffffffffULL)) : 0;
      int h2=tid<<1;
      float v0=tanhf(reconf(p.T0h[tok*1024+h2],  p.T0l[tok*1024+h2])   + p.u0[b*1024+h2]);
      float v1=tanhf(reconf(p.T0h[tok*1024+h2+1],p.T0l[tok*1024+h2+1]) + p.u0[b*1024+h2+1]);
      uint32_t ph_,pl_; pack2(v0,v1,ph_,pl_);
      st_u32((uint32_t*)p.dh0h + ((b*1024+h2)>>1), ph_);
      st_u32((uint32_t*)p.dh0l + ((b*1024+h2)>>1), pl_);
    }
    ++phx; gbar(p.bar1, phx<<8);

    // ---- P2: w1x = Wih1.dh0 -> h1 = tanh(w1x+bih1+u1); u0' = Whh0.dh0+bhh0 ----
    dmm_dual(lane,wave, p.dh0h,p.dh0l, p.dh0h,p.dh0l,
             wih1h,wih1l, whh0h,whh0l, ldsD);
    __syncthreads();
    if (tid<128){
      int b=tid&63, jp=tid>>6;
      float nv[2];
      #pragma unroll
      for (int d=0;d<2;++d){
        int j=(jp<<1)+d, col=j0+j;
        nv[d] = tanhf(ldsD[j*68+b] + cb[0*4+j] + p.u1[b*1024+col]);
      }
      uint32_t ph_,pl_; pack2(nv[0],nv[1],ph_,pl_);
      int c0=j0+(jp<<1);
      st_u32((uint32_t*)p.dh1h + ((b*1024+c0)>>1), ph_);
      st_u32((uint32_t*)p.dh1l + ((b*1024+c0)>>1), pl_);
      st_u32((uint32_t*)p.cath + ((b*2048+c0)>>1), ph_);
      st_u32((uint32_t*)p.catl + ((b*2048+c0)>>1), pl_);
    } else if (tid<256){
      int t2=tid-128; int b=t2&63, jp=t2>>6;
      #pragma unroll
      for (int d=0;d<2;++d){
        int j=(jp<<1)+d, col=j0+j;
        st_f32(p.u0 + b*1024+col, ldsD[272+j*68+b] + cb[1*4+j]);
      }
    }
    ++phx; gbar(p.bar1, phx<<8);

    // ---- P3: q = hq.dh1 + hqb ; u1' = Whh1.dh1 + bhh1 ----
    dmm_dual(lane,wave, p.dh1h,p.dh1l, p.dh1h,p.dh1l,
             hqh2,hql2, whh1h,whh1l, ldsD);
    __syncthreads();
    if (tid<256){
      int b=tid&63, j=tid>>6, col=j0+j;
      st_f32(p.q  + b*1024+col, ldsD[j*68+b]     + cb[2*4+j]);
      st_f32(p.u1 + b*1024+col, ldsD[272+j*68+b] + cb[3*4+j]);
    }
    ++phx; gbar(p.bar1, phx<<8);

    // ---- P4: flash attention quarter (b = bid>>2, q4 = bid&3), enc f16 ----
    {
      const int b=bid>>2, q4=bid&3, s0=q4<<7;
      const uint32_t* eb = p.enc_att + ((size_t)b*SH>>1);
      float qv[16];
      #pragma unroll
      for (int i=0;i<8;++i){
        float2 qq = *(const float2*)(p.q + b*1024 + (((i<<6)+lane)<<1));
        qv[2*i]=qq.x; qv[2*i+1]=qq.y;
      }
      float ov[16];
      #pragma unroll
      for (int i=0;i<16;++i) ov[i]=0.f;
      float mrun=-3.0e38f, lrun=0.f;
      for (int si=0; si<16; ++si){
        int s = s0 + (wave<<4) + si;
        const uint32_t* ep = eb + s*512 + lane;
        float ef[16]; float partial=0.f;
        #pragma unroll
        for (int i=0;i<8;++i){
          uint32_t w2 = ep[i<<6];
          float e0=(float)__builtin_bit_cast(_Float16,(unsigned short)(w2&0xffffu));
          float e1=(float)__builtin_bit_cast(_Float16,(unsigned short)(w2>>16));
          ef[2*i]=e0; ef[2*i+1]=e1;
          partial = fmaf(e1,qv[2*i+1], fmaf(e0,qv[2*i], partial));
        }
        #pragma unroll
        for (int off=32; off; off>>=1) partial += __shfl_xor(partial, off, 64);
        if (t==63 && lane==0) st_f32(p.sc63 + b*512 + s, partial);
        float mnew=fmaxf(mrun,partial);
        float fac=__expf(mrun-mnew), w=__expf(partial-mnew);
        lrun = fmaf(lrun,fac,w);
        #pragma unroll
        for (int i=0;i<16;++i) ov[i]=fmaf(ov[i],fac,w*ef[i]);
        mrun=mnew;
      }
      if (lane==0){ sml[wave]=mrun; sml[8+wave]=lrun; }
      __syncthreads();
      float Mx=sml[0];
      #pragma unroll
      for (int w=1;w<8;++w) Mx=fmaxf(Mx,sml[w]);
      float fw=__expf(sml[wave]-Mx);
      if (wave<4){
        #pragma unroll
        for (int i=0;i<8;++i){
          int h=((i<<6)+lane)<<1;
          sbufA[wave*1032+h]  =fw*ov[2*i];
          sbufA[wave*1032+h+1]=fw*ov[2*i+1];
        }
      }
      __syncthreads();
      if (wave>=4){
        #pragma unroll
        for (int i=0;i<8;++i){
          int h=((i<<6)+lane)<<1;
          sbufA[(wave-4)*1032+h]  +=fw*ov[2*i];
          sbufA[(wave-4)*1032+h+1]+=fw*ov[2*i+1];
        }
      }
      __syncthreads();
      if (tid==0){
        float L=0.f;
        #pragma unroll
        for (int w=0;w<8;++w) L += __expf(sml[w]-Mx)*sml[8+w];
        st_f32(p.attp_ml + (b*4+q4)*2,   Mx);
        st_f32(p.attp_ml + (b*4+q4)*2+1, L);
      }
      { int h2=tid<<1;
        float o0=sbufA[h2]+sbufA[1032+h2]+sbufA[2064+h2]+sbufA[3096+h2];
        float o1=sbufA[h2+1]+sbufA[1032+h2+1]+sbufA[2064+h2+1]+sbufA[3096+h2+1];
        st_f32(p.attp_o + (b*4+q4)*1024 + h2,   o0);
        st_f32(p.attp_o + (b*4+q4)*1024 + h2+1, o1);
      }
    }
    ++phx; gbar(p.bar1, phx<<8);

    // ---- P5: combine quarters -> att into cat[:,1024:]; t=63: attn output ----
    if (bid < 64){
      const int b=bid;
      float m0=p.attp_ml[b*8+0], l0=p.attp_ml[b*8+1];
      float m1=p.attp_ml[b*8+2], l1=p.attp_ml[b*8+3];
      float m2=p.attp_ml[b*8+4], l2=p.attp_ml[b*8+5];
      float m3=p.attp_ml[b*8+6], l3=p.attp_ml[b*8+7];
      float Mx=fmaxf(fmaxf(m0,m1),fmaxf(m2,m3));
      float f0=expf(m0-Mx),f1=expf(m1-Mx),f2=expf(m2-Mx),f3=expf(m3-Mx);
      float invL=1.0f/(f0*l0+f1*l1+f2*l2+f3*l3);
      int h2=tid<<1;
      float o0=(f0*p.attp_o[(b*4+0)*1024+h2]+f1*p.attp_o[(b*4+1)*1024+h2]
               +f2*p.attp_o[(b*4+2)*1024+h2]+f3*p.attp_o[(b*4+3)*1024+h2])*invL;
      float o1=(f0*p.attp_o[(b*4+0)*1024+h2+1]+f1*p.attp_o[(b*4+1)*1024+h2+1]
               +f2*p.attp_o[(b*4+2)*1024+h2+1]+f3*p.attp_o[(b*4+3)*1024+h2+1])*invL;
      uint32_t ph_,pl_; pack2(o0,o1,ph_,pl_);
      st_u32((uint32_t*)p.cath + ((b*2048+1024+h2)>>1), ph_);
      st_u32((uint32_t*)p.catl + ((b*2048+1024+h2)>>1), pl_);
      if (t==63)
        st_f32(p.dout + OFF_ATTN + b*512 + tid, expf(p.sc63[b*512+tid]-Mx)*invL);
    }
    ++phx; gbar(p.bar1, phx<<8);

    // ---- P6: c = comb_W.[h1|att] + comb_b ----
    dmm_sk<2048>(lane,wave, p.cath, p.catl, combh2, combl2, ldsD);
    __syncthreads();
    if (tid<128){
      int b=tid&63, jp=tid>>6;
      float nv[2];
      #pragma unroll
      for (int d=0;d<2;++d){
        int j=(jp<<1)+d;
        nv[d] = ldsD[j*68+b] + ldsD[272+j*68+b] + cb[4*4+j];
      }
      uint32_t ph_,pl_; pack2(nv[0],nv[1],ph_,pl_);
      int c0=j0+(jp<<1);
      st_u32((uint32_t*)p.ch + ((b*1024+c0)>>1), ph_);
      st_u32((uint32_t*)p.cl + ((b*1024+c0)>>1), pl_);
    }
    ++phx; gbar(p.bar1, phx<<8);

    // ---- P7: logits = fc.c + fc_b -> dout + argmax partials ----
    dmm_sk<1024>(lane,wave, p.ch, p.cl, fch2, fcl2, ldsD);
    __syncthreads();
    if (tid<256){
      int b=tid&63, j=tid>>6, col=j0+j;
      float val = ldsD[j*68+b] + ldsD[272+j*68+b] + cb[5*4+j];
      st_f32(p.dout + b*65536 + t*1024 + col, val);
      ldsL[j*68+b] = val;
    }
    __syncthreads();
    if (tid<64){
      int b=tid; float best=-3.0e38f; int bi=0;
      #pragma unroll
      for (int j=0;j<4;++j){
        float v=ldsL[j*68+b];
        if (v>best){ best=v; bi=j; }
      }
      st_u64(p.amax + b*256 + bid,
             ((unsigned long long)ordf(best)<<32) | (unsigned)(1023-(j0+bi)));
    }
    ++phx; gbar(p.bar1, phx<<8);
  }

  // ---- final hidden output [2][B][H] ----
  { int idx=bid*512+tid;
    int i=idx&65535;
    float v=(idx>>16)? reconf(p.dh1h[i],p.dh1l[i]) : reconf(p.dh0h[i],p.dh0l[i]);
    st_f32(p.dout + OFF_HID + idx, v);
  }
}

// ---------------- host ----------------
extern "C" void kernel_launch(void* const* d_in, const int* in_sizes, int n_in,
                              void* d_out, int out_size, void* d_ws, size_t ws_size,
                              hipStream_t stream)
{
  (void)in_sizes; (void)n_in; (void)out_size;
  P p;
  p.x     = (const float*)d_in[0];  p.emb   = (const float*)d_in[1];
  p.eWih0 = (const float*)d_in[2];  p.eWhh0 = (const float*)d_in[3];
  p.ebih0 = (const float*)d_in[4];  p.ebhh0 = (const float*)d_in[5];
  p.dWih0 = (const float*)d_in[6];  p.dWhh0 = (const float*)d_in[7];
  p.dbih0 = (const float*)d_in[8];  p.dbhh0 = (const float*)d_in[9];
  p.eWih1 = (const float*)d_in[10]; p.eWhh1 = (const float*)d_in[11];
  p.ebih1 = (const float*)d_in[12]; p.ebhh1 = (const float*)d_in[13];
  p.dWih1 = (const float*)d_in[14]; p.dWhh1 = (const float*)d_in[15];
  p.dbih1 = (const float*)d_in[16]; p.dbhh1 = (const float*)d_in[17];
  p.hqW   = (const float*)d_in[18]; p.hqb   = (const float*)d_in[19];
  p.combW = (const float*)d_in[20]; p.combb = (const float*)d_in[21];
  p.fcW   = (const float*)d_in[22]; p.fcb   = (const float*)d_in[23];
  p.dout  = (float*)d_out;

  char* base = (char*)d_ws; size_t off = 0;
  auto alloc = [&](size_t bytes)->char*{
    char* r = base + off; off = (off + bytes + 255) & ~(size_t)255; return r;
  };
  p.enc_att = (uint32_t*)alloc(16777216ULL*4);     // 64 MB f16 enc_outs
  p.embh  = (_Float16*)alloc(1048576ULL*2); p.embl  = (_Float16*)alloc(1048576ULL*2);
  p.T0h   = (_Float16*)alloc(1048576ULL*2); p.T0l   = (_Float16*)alloc(1048576ULL*2);
  p.wih0dh= (_Float16*)alloc(1048576ULL*2); p.wih0dl= (_Float16*)alloc(1048576ULL*2);
  p.h0h   = (_Float16*)alloc(131072ULL*2);  p.h0l   = (_Float16*)alloc(131072ULL*2);
  p.h1h   = (_Float16*)alloc(131072ULL*2);  p.h1l   = (_Float16*)alloc(131072ULL*2);
  p.dh0h  = (_Float16*)alloc(65536ULL*2);   p.dh0l  = (_Float16*)alloc(65536ULL*2);
  p.dh1h  = (_Float16*)alloc(65536ULL*2);   p.dh1l  = (_Float16*)alloc(65536ULL*2);
  p.cath  = (_Float16*)alloc(131072ULL*2);  p.catl  = (_Float16*)alloc(131072ULL*2);
  p.ch    = (_Float16*)alloc(65536ULL*2);   p.cl    = (_Float16*)alloc(65536ULL*2);
  p.u0    = (float*)alloc(65536ULL*4);      p.u1    = (float*)alloc(65536ULL*4);
  p.q     = (float*)alloc(65536ULL*4);
  p.attp_o  = (float*)alloc(262144ULL*4);
  p.attp_ml = (float*)alloc(512ULL*4);
  p.sc63    = (float*)alloc(32768ULL*4);
  p.amax    = (unsigned long long*)alloc(16384ULL*8);
  { unsigned* bars = (unsigned*)alloc(512*4);
    p.bar0 = bars; p.bar1 = bars + 256; }
  if (off > ws_size) return;

  hipFuncSetAttribute(reinterpret_cast<const void*>(k_encp),
                      hipFuncAttributeMaxDynamicSharedMemorySize, ENC_LDS);
  hipFuncSetAttribute(reinterpret_cast<const void*>(k_decp),
                      hipFuncAttributeMaxDynamicSharedMemorySize, DEC_LDS);

  k_split<<<2048,256,0,stream>>>(p.emb,   p.embh,   p.embl,   1048576);
  k_split<<<2048,256,0,stream>>>(p.dWih0, p.wih0dh, p.wih0dl, 1048576);
  k_zero <<<256,256,0,stream>>>(p);
  k_t0   <<<1024,256,0,stream>>>(p);
  k_encp <<<256,512,ENC_LDS,stream>>>(p);
  k_decp <<<256,512,DEC_LDS,stream>>>(p);
}

// Round 4
// 37916.925 us; speedup vs baseline: 1.2193x; 1.0566x over previous
//
#include <hip/hip_runtime.h>
#include <stdint.h>

// ---------------------------------------------------------------------------
// Round 4: same persistent structure as round 3, with the barrier fixed:
// RELAXED system-scope add (release-RMW emitted buffer_wbl2 = full L2 walk
// per barrier = the 30-40us/barrier cost). Consumer side keeps acquire-only
// fence (inv, no writeback). Plus: x-load hoist, LDS f32 h-cache for the
// z-blend, deeper A-load unroll.
// ---------------------------------------------------------------------------

#define BB 64
#define SS 512
#define TT 64
#define HH 1024
#define VV 1024
#define BH 65536   // B*H
#define SH 524288  // S*H
#define OFF_HID  4194304           // B*T*V
#define OFF_ATTN 4325376           // + L*B*H

#define ENC_LDS 160864
#define DEC_LDS 137472

typedef _Float16 half8  __attribute__((ext_vector_type(8)));
typedef float    floatx4 __attribute__((ext_vector_type(4)));

#define MFMA16(a,b,c) __builtin_amdgcn_mfma_f32_16x16x32_f16(a,b,c,0,0,0)

struct P {
  const float *x, *emb;
  const float *eWih0, *eWhh0, *ebih0, *ebhh0;
  const float *dWih0, *dWhh0, *dbih0, *dbhh0;
  const float *eWih1, *eWhh1, *ebih1, *ebhh1;
  const float *dWih1, *dWhh1, *dbih1, *dbhh1;
  const float *hqW, *hqb, *combW, *combb, *fcW, *fcb;
  uint32_t* enc_att;               // [B][S][H] f16, 2 per u32
  _Float16 *embh,*embl,*T0h,*T0l;  // T0 = emb @ dWih0^T + dbih0  [V][H] pairs
  _Float16 *wih0dh,*wih0dl;
  _Float16 *h0h,*h0l,*h1h,*h1l;    // [2][B*H] parity-double-buffered enc states
  _Float16 *dh0h,*dh0l,*dh1h,*dh1l;// decoder states [B*H]
  _Float16 *cath,*catl;            // [B][2048] = [h1 | att] pairs
  _Float16 *ch,*cl;                // comb output pairs [B*H]
  float *u0,*u1,*q;                // fp32 [B*H]
  float *attp_o;                   // [B][4][H]
  float *attp_ml;                  // [B][4][2]
  float *sc63;                     // [B][S] raw scores at t=63
  unsigned long long* amax;        // [B][256] argmax partials
  unsigned *bar0, *bar1;           // 4-way-spread grid-barrier counters
  float* dout;
};

// ---------------- helpers ----------------
__device__ __forceinline__ void splitf(float x, _Float16& hi, _Float16& lo){
  _Float16 h = (_Float16)x; hi = h;
  lo = (_Float16)((x - (float)h) * 2048.0f);
}
__device__ __forceinline__ float reconf(_Float16 hi, _Float16 lo){
  return fmaf((float)lo, 1.0f/2048.0f, (float)hi);
}
__device__ __forceinline__ unsigned ordf(float f){
  unsigned u = __float_as_uint(f);
  return (u & 0x80000000u) ? ~u : (u | 0x80000000u);
}
__device__ __forceinline__ void pack2(float v0, float v1, uint32_t& ph, uint32_t& pl){
  _Float16 h0,l0,h1,l1; splitf(v0,h0,l0); splitf(v1,h1,l1);
  ph = (uint32_t)__builtin_bit_cast(unsigned short,h0)
     | ((uint32_t)__builtin_bit_cast(unsigned short,h1) << 16);
  pl = (uint32_t)__builtin_bit_cast(unsigned short,l0)
     | ((uint32_t)__builtin_bit_cast(unsigned short,l1) << 16);
}
// system-scope stores: bypass L2 (coherent at L3) so the barrier needs no wbl2
__device__ __forceinline__ void st_u32(uint32_t* p2, uint32_t v){
  __hip_atomic_store(p2, v, __ATOMIC_RELAXED, __HIP_MEMORY_SCOPE_SYSTEM);
}
__device__ __forceinline__ void st_f32(float* p2, float v){
  __hip_atomic_store(p2, v, __ATOMIC_RELAXED, __HIP_MEMORY_SCOPE_SYSTEM);
}
__device__ __forceinline__ void st_u64(unsigned long long* p2, unsigned long long v){
  __hip_atomic_store(p2, v, __ATOMIC_RELAXED, __HIP_MEMORY_SCOPE_SYSTEM);
}

// Grid barrier. RELAXED add: __syncthreads has already drained each wave's
// write-through system stores (vmcnt 0 before s_barrier), so the add needs no
// release — release-RMW at system scope emits buffer_wbl2 (full L2 walk) and
// was costing ~30-40us per barrier. Acquire-only fence on exit (inv, no wb).
__device__ __forceinline__ void gbar(unsigned* c, unsigned target){
  __syncthreads();
  if (threadIdx.x == 0){
    __hip_atomic_fetch_add(c + (blockIdx.x & 3)*64, 1u,
                           __ATOMIC_RELAXED, __HIP_MEMORY_SCOPE_SYSTEM);
    unsigned s;
    do {
      __builtin_amdgcn_s_sleep(1);
      s = __hip_atomic_load(c,       __ATOMIC_RELAXED, __HIP_MEMORY_SCOPE_SYSTEM)
        + __hip_atomic_load(c + 64,  __ATOMIC_RELAXED, __HIP_MEMORY_SCOPE_SYSTEM)
        + __hip_atomic_load(c + 128, __ATOMIC_RELAXED, __HIP_MEMORY_SCOPE_SYSTEM)
        + __hip_atomic_load(c + 192, __ATOMIC_RELAXED, __HIP_MEMORY_SCOPE_SYSTEM);
    } while (s < target);
  }
  __syncthreads();
  __builtin_amdgcn_fence(__ATOMIC_ACQUIRE, "agent");   // inv L1+L2, no wbl2
}

// ---------------- split-precision GEMM core (k_t0 only) ----------------
template<int NT, int KH, bool SPLIT>
__device__ __forceinline__ void gemm_core(
    const _Float16* __restrict__ Ah0, const _Float16* __restrict__ Al0,
    const _Float16* __restrict__ Ah1, const _Float16* __restrict__ Al1,
    int sA,
    const _Float16* __restrict__ Wh, const _Float16* __restrict__ Wl,
    int nrows, _Float16* ldsW, float* accOut)
{
  const int tid = threadIdx.x, lane = tid & 63, wave = tid >> 6;
  const int mA = (wave<<4) + (lane & 15);
  const int kb = ((lane>>4) << 3);
  const int wstride = KH << 10;
  floatx4 aH[NT], aM1[NT], aM2[NT];
  int ne[NT];
  const _Float16* bh_base[NT];
  const _Float16* bl_base[NT];
  #pragma unroll
  for (int nt=0; nt<NT; ++nt){
    int nn = (lane & 15) + (nt<<4);
    ne[nt] = nn < nrows ? nn : nrows - 1;
    bh_base[nt] = ldsW + ne[nt]*1032 + kb;
    aH[nt]  = floatx4{0.f,0.f,0.f,0.f};
    aM1[nt] = floatx4{0.f,0.f,0.f,0.f};
    aM2[nt] = floatx4{0.f,0.f,0.f,0.f};
  }
  #pragma unroll
  for (int kh=0; kh<KH; ++kh){
    __syncthreads();
    const int iters = (nrows*128 + 255) >> 8;
    for (int it=0; it<iters; ++it){
      int idx = tid + (it<<8);
      int row = idx >> 7, col = (idx & 127) << 3;
      if (row < nrows)
        *(half8*)(ldsW + row*1032 + col) =
            *(const half8*)(Wh + row*wstride + (kh<<10) + col);
    }
    __syncthreads();
    const _Float16* ah_p = ((KH==2 && kh==1) ? Ah1 : Ah0) + mA*sA + kb;
    const _Float16* al_p = ((KH==2 && kh==1) ? Al1 : Al0) + mA*sA + kb;
    #pragma unroll
    for (int nt=0; nt<NT; ++nt) bl_base[nt] = Wl + ne[nt]*wstride + (kh<<10) + kb;
    #pragma unroll 4
    for (int ks=0; ks<32; ++ks){
      half8 ah = *(const half8*)(ah_p + (ks<<5));
      half8 al = *(const half8*)(al_p + (ks<<5));
      #pragma unroll
      for (int nt=0; nt<NT; ++nt){
        half8 bh = *(const half8*)(bh_base[nt] + (ks<<5));
        half8 bl = *(const half8*)(bl_base[nt] + (ks<<5));
        aH[nt]  = MFMA16(ah, bh, aH[nt]);
        aM1[nt] = MFMA16(ah, bl, aM1[nt]);
        aM2[nt] = MFMA16(al, bh, aM2[nt]);
      }
    }
  }
  #pragma unroll
  for (int nt=0; nt<NT; ++nt)
    #pragma unroll
    for (int r=0;r<4;++r)
      accOut[nt*4 + r] = aH[nt][r] + (aM1[nt][r] + aM2[nt][r]) * (1.f/2048.f);
}

// ---------------- prologue kernels ----------------
__global__ __launch_bounds__(256) void k_split(const float* __restrict__ src,
                                               _Float16* dh, _Float16* dl, int n){
  for (int i = blockIdx.x*256 + threadIdx.x; i < n; i += gridDim.x*256){
    _Float16 hi,lo; splitf(src[i],hi,lo); dh[i]=hi; dl[i]=lo;
  }
}
__global__ __launch_bounds__(256) void k_zero(P p){
  int i = blockIdx.x*256 + threadIdx.x;   // grid 256 -> 65536 threads
  p.h1h[i] = (_Float16)0.f; p.h1l[i] = (_Float16)0.f;           // h1 parity 0
  p.h0h[BH + i] = (_Float16)0.f; p.h0l[BH + i] = (_Float16)0.f; // h0 parity 1
  if (i < 512) p.bar0[i] = 0u;            // both barrier sets (bar1 = bar0+256)
}
// T0[v][j] = emb[v] . dWih0[j] + dbih0[j]
__global__ __launch_bounds__(256) void k_t0(P p){
  __shared__ _Float16 ldsW[16*1032];
  const int ns = blockIdx.x & 63, mc = blockIdx.x >> 6;
  float acc[4];
  gemm_core<1,1,false>(p.embh + mc*65536, p.embl + mc*65536, nullptr, nullptr, 1024,
                       p.wih0dh + ns*16*1024, p.wih0dl + ns*16*1024, 16, ldsW, acc);
  const int lane = threadIdx.x & 63, wave = threadIdx.x >> 6;
  const int n = lane & 15, col = (ns<<4) + n;
  const float bv = p.dbih0[col];
  #pragma unroll
  for (int r=0;r<4;++r){
    int v = mc*64 + (wave<<4) + ((lane>>4)<<2) + r;
    _Float16 hi,lo; splitf(acc[r] + bv, hi, lo);
    p.T0h[v*1024 + col] = hi; p.T0l[v*1024 + col] = lo;
  }
}

// ---------------- persistent encoder ----------------
// 256 blocks x 512 thr; block owns 4 output cols j of BOTH layers.
// LDS: W0/W1 split pairs, reduction ldsA[36][68], consts, f32 h-cache.
__global__ __launch_bounds__(512,1) void k_encp(P p){
  extern __shared__ char smem[];
  _Float16* W0h = (_Float16*)smem;       // 12*1032
  _Float16* W0l = W0h + 12384;
  _Float16* W1h = W0l + 12384;           // 12*2056
  _Float16* W1l = W1h + 24672;
  float* ldsA = (float*)(smem + 148224); // [36][68]
  float* ldsC = ldsA + 2448;             // [12][6]
  float* ldsH0 = (float*)(smem + 158304);// [64][5] f32 own-col h cache
  float* ldsH1 = (float*)(smem + 159584);// [64][5]
  const int tid = threadIdx.x, lane = tid & 63, wave = tid >> 6;
  const int bid = blockIdx.x, j0 = bid << 2;

  for (int idx=tid; idx<12*1024; idx+=512){
    int r=idx>>10, k=idx&1023;
    int grow=(r>>2)*1024 + j0 + (r&3);
    _Float16 hi,lo; splitf(p.eWhh0[grow*1024+k],hi,lo);
    W0h[r*1032+k]=hi; W0l[r*1032+k]=lo;
  }
  for (int idx=tid; idx<12*2048; idx+=512){
    int r=idx>>11, k=idx&2047;
    int grow=(r>>2)*1024 + j0 + (r&3);
    float v = (k<1024)? p.eWhh1[grow*1024+k] : p.eWih1[grow*1024+(k-1024)];
    _Float16 hi,lo; splitf(v,hi,lo);
    W1h[r*2056+k]=hi; W1l[r*2056+k]=lo;
  }
  if (tid<12){
    int grow=(tid>>2)*1024 + j0 + (tid&3);
    ldsC[tid*6+0]=p.eWih0[grow*2+0]; ldsC[tid*6+1]=p.eWih0[grow*2+1];
    ldsC[tid*6+2]=p.ebih0[grow];     ldsC[tid*6+3]=p.ebhh0[grow];
    ldsC[tid*6+4]=p.ebih1[grow];     ldsC[tid*6+5]=p.ebhh1[grow];
  }
  if (tid < 256){
    ldsH0[(tid&63)*5 + (tid>>6)] = 0.f;
    ldsH1[(tid&63)*5 + (tid>>6)] = 0.f;
  }
  __syncthreads();

  const int ln15 = lane & 15, kb = (lane >> 4) << 3;
  const bool isl1 = wave >= 4;
  const int mt = wave & 3;
  const int brow = (ln15 < 12) ? ln15 : 11;
  const int mrow = (mt<<4) + ln15;
  const int msub = (mt<<4) + ((lane>>4)<<2);

  #pragma unroll 1
  for (int e=0; e<=512; ++e){
    const int cur=e&1, prv=cur^1;
    // hoisted x-loads (post-inv L3 reads hidden under the MFMA loop)
    float xv0=0.f, xv1=0.f;
    if (tid < 128 && e < 512){
      const int b2 = tid & 63;
      xv0 = p.x[b2*1024 + e]; xv1 = p.x[b2*1024 + 512 + e];
    }
    if (!isl1){
      if (e < 512){
        const _Float16* ah = p.h0h + prv*BH + mrow*1024 + kb;
        const _Float16* al = p.h0l + prv*BH + mrow*1024 + kb;
        const _Float16* bh = W0h + brow*1032 + kb;
        const _Float16* bl = W0l + brow*1032 + kb;
        floatx4 H{0,0,0,0},M{0,0,0,0},N{0,0,0,0};
        #pragma unroll 16
        for (int ks=0;ks<32;++ks){
          int off=ks<<5;
          half8 A=*(const half8*)(ah+off), Alo=*(const half8*)(al+off);
          half8 B=*(const half8*)(bh+off), Blo=*(const half8*)(bl+off);
          H=MFMA16(A,B,H); M=MFMA16(A,Blo,M); N=MFMA16(Alo,B,N);
        }
        if (ln15<12){
          #pragma unroll
          for (int r=0;r<4;++r)
            ldsA[ln15*68 + msub + r] = H[r] + (M[r]+N[r])*(1.f/2048.f);
        }
      }
    } else {
      if (e >= 1){
        const _Float16* a1h = p.h1h + prv*BH + mrow*1024 + kb;
        const _Float16* a1l = p.h1l + prv*BH + mrow*1024 + kb;
        const _Float16* a0h = p.h0h + prv*BH + mrow*1024 + kb;
        const _Float16* a0l = p.h0l + prv*BH + mrow*1024 + kb;
        const _Float16* bh = W1h + brow*2056 + kb;
        const _Float16* bl = W1l + brow*2056 + kb;
        floatx4 H1{0,0,0,0},M1{0,0,0,0},N1{0,0,0,0};
        floatx4 H2{0,0,0,0},M2{0,0,0,0},N2{0,0,0,0};
        #pragma unroll 8
        for (int ks=0;ks<32;++ks){
          int off=ks<<5;
          half8 A=*(const half8*)(a1h+off), Alo=*(const half8*)(a1l+off);
          half8 B=*(const half8*)(bh+off), Blo=*(const half8*)(bl+off);
          H1=MFMA16(A,B,H1); M1=MFMA16(A,Blo,M1); N1=MFMA16(Alo,B,N1);
        }
        #pragma unroll 8
        for (int ks=0;ks<32;++ks){
          int off=ks<<5;
          half8 A=*(const half8*)(a0h+off), Alo=*(const half8*)(a0l+off);
          half8 B=*(const half8*)(bh+1024+off), Blo=*(const half8*)(bl+1024+off);
          H2=MFMA16(A,B,H2); M2=MFMA16(A,Blo,M2); N2=MFMA16(Alo,B,N2);
        }
        if (ln15<12){
          #pragma unroll
          for (int r=0;r<4;++r){
            ldsA[(12+ln15)*68 + msub + r] = H1[r] + (M1[r]+N1[r])*(1.f/2048.f);
            ldsA[(24+ln15)*68 + msub + r] = H2[r] + (M2[r]+N2[r])*(1.f/2048.f);
          }
        }
      }
    }
    __syncthreads();
    if (tid < 256){
      const bool l1t = tid >= 128;
      const int b = tid & 63, jp = (tid>>6) & 1;
      const int c0 = j0 + (jp<<1);
      if (!l1t && e < 512){
        float nv[2];
        #pragma unroll
        for (int d=0; d<2; ++d){
          int jj=(jp<<1)+d, r0=jj, r1=4+jj, r2=8+jj;
          float hr = ldsA[r0*68+b] + ldsC[r0*6+3];
          float hz = ldsA[r1*68+b] + ldsC[r1*6+3];
          float hn = ldsA[r2*68+b] + ldsC[r2*6+3];
          float xr = fmaf(xv0, ldsC[r0*6+0], fmaf(xv1, ldsC[r0*6+1], ldsC[r0*6+2]));
          float xz = fmaf(xv0, ldsC[r1*6+0], fmaf(xv1, ldsC[r1*6+1], ldsC[r1*6+2]));
          float xn = fmaf(xv0, ldsC[r2*6+0], fmaf(xv1, ldsC[r2*6+1], ldsC[r2*6+2]));
          float rg = 1.0f/(1.0f + expf(-(xr+hr)));
          float zg = 1.0f/(1.0f + expf(-(xz+hz)));
          float ng = tanhf(xn + rg*hn);
          float hold = ldsH0[b*5+jj];
          nv[d] = (1.0f - zg)*ng + zg*hold;
          ldsH0[b*5+jj] = nv[d];
        }
        uint32_t ph_,pl_; pack2(nv[0],nv[1],ph_,pl_);
        st_u32((uint32_t*)(p.h0h + cur*BH) + ((b*1024+c0)>>1), ph_);
        st_u32((uint32_t*)(p.h0l + cur*BH) + ((b*1024+c0)>>1), pl_);
      } else if (l1t && e >= 1){
        const int t = e-1;
        float nv[2];
        #pragma unroll
        for (int d=0; d<2; ++d){
          int jj=(jp<<1)+d, r0=jj, r1=4+jj, r2=8+jj;
          float hr = ldsA[(12+r0)*68+b] + ldsC[r0*6+5];
          float hz = ldsA[(12+r1)*68+b] + ldsC[r1*6+5];
          float hn = ldsA[(12+r2)*68+b] + ldsC[r2*6+5];
          float xr = ldsA[(24+r0)*68+b] + ldsC[r0*6+4];
          float xz = ldsA[(24+r1)*68+b] + ldsC[r1*6+4];
          float xn = ldsA[(24+r2)*68+b] + ldsC[r2*6+4];
          float rg = 1.0f/(1.0f + expf(-(xr+hr)));
          float zg = 1.0f/(1.0f + expf(-(xz+hz)));
          float ng = tanhf(xn + rg*hn);
          float hold = ldsH1[b*5+jj];
          nv[d] = (1.0f - zg)*ng + zg*hold;
          ldsH1[b*5+jj] = nv[d];
        }
        uint32_t ph_,pl_; pack2(nv[0],nv[1],ph_,pl_);
        st_u32((uint32_t*)(p.h1h + cur*BH) + ((b*1024+c0)>>1), ph_);
        st_u32((uint32_t*)(p.h1l + cur*BH) + ((b*1024+c0)>>1), pl_);
        _Float16 e0=(_Float16)nv[0], e1=(_Float16)nv[1];
        uint32_t pe = (uint32_t)__builtin_bit_cast(unsigned short,e0)
                    | ((uint32_t)__builtin_bit_cast(unsigned short,e1) << 16);
        st_u32(p.enc_att + (((size_t)b*SH + t*1024 + c0)>>1), pe);
      }
    }
    gbar(p.bar0, (unsigned)(e+1) << 8);
  }
}

// ---------------- decoder GEMM helpers (weights in LDS) ----------------
__device__ __forceinline__ void dmm_dual(int lane, int wave,
    const _Float16* A0h, const _Float16* A0l,
    const _Float16* A1h, const _Float16* A1l,
    const _Float16* W0h_, const _Float16* W0l_,
    const _Float16* W1h_, const _Float16* W1l_,
    float* ldsD)
{
  const int mt = wave>>1, sel = wave&1;
  const int ln15 = lane&15, kb = (lane>>4)<<3, n = ln15&3;
  const _Float16* ah = (sel? A1h:A0h) + ((mt<<4)+ln15)*1024 + kb;
  const _Float16* al = (sel? A1l:A0l) + ((mt<<4)+ln15)*1024 + kb;
  const _Float16* bh = (sel? W1h_:W0h_) + n*1032 + kb;
  const _Float16* bl = (sel? W1l_:W0l_) + n*1032 + kb;
  floatx4 H{0,0,0,0},M{0,0,0,0},N{0,0,0,0};
  #pragma unroll 8
  for (int ks=0;ks<32;++ks){
    int off=ks<<5;
    half8 A=*(const half8*)(ah+off), Alo=*(const half8*)(al+off);
    half8 B=*(const half8*)(bh+off), Blo=*(const half8*)(bl+off);
    H=MFMA16(A,B,H); M=MFMA16(A,Blo,M); N=MFMA16(Alo,B,N);
  }
  if (ln15 < 4){
    #pragma unroll
    for (int r=0;r<4;++r)
      ldsD[sel*272 + n*68 + (mt<<4)+((lane>>4)<<2)+r] = H[r]+(M[r]+N[r])*(1.f/2048.f);
  }
}
template<int K>
__device__ __forceinline__ void dmm_sk(int lane, int wave,
    const _Float16* Ah, const _Float16* Al,
    const _Float16* Wh_, const _Float16* Wl_,
    float* ldsD)
{
  const int mt = wave>>1, kg = wave&1;
  const int ln15 = lane&15, kb = (lane>>4)<<3, n = ln15&3;
  const int k0 = kg*(K/2);
  const _Float16* ah = Ah + ((mt<<4)+ln15)*K + k0 + kb;
  const _Float16* al = Al + ((mt<<4)+ln15)*K + k0 + kb;
  const _Float16* bh = Wh_ + n*(K+8) + k0 + kb;
  const _Float16* bl = Wl_ + n*(K+8) + k0 + kb;
  floatx4 H{0,0,0,0},M{0,0,0,0},N{0,0,0,0};
  #pragma unroll 8
  for (int ks=0;ks<K/64;++ks){
    int off=ks<<5;
    half8 A=*(const half8*)(ah+off), Alo=*(const half8*)(al+off);
    half8 B=*(const half8*)(bh+off), Blo=*(const half8*)(bl+off);
    H=MFMA16(A,B,H); M=MFMA16(A,Blo,M); N=MFMA16(Alo,B,N);
  }
  if (ln15 < 4){
    #pragma unroll
    for (int r=0;r<4;++r)
      ldsD[kg*272 + n*68 + (mt<<4)+((lane>>4)<<2)+r] = H[r]+(M[r]+N[r])*(1.f/2048.f);
  }
}

// ---------------- persistent decoder ----------------
__global__ __launch_bounds__(512,1) void k_decp(P p){
  extern __shared__ char smem[];
  _Float16* wih1h=(_Float16*)smem;      _Float16* wih1l=wih1h+4128;
  _Float16* whh0h=wih1l+4128;           _Float16* whh0l=whh0h+4128;
  _Float16* hqh2 =whh0l+4128;           _Float16* hql2 =hqh2+4128;
  _Float16* whh1h=hql2+4128;            _Float16* whh1l=whh1h+4128;
  _Float16* fch2 =whh1l+4128;           _Float16* fcl2 =fch2+4128;
  _Float16* combh2=fcl2+4128;           _Float16* combl2=combh2+8224;
  float* sbufA=(float*)(smem+115456);   // [4][1032]
  float* ldsD =(float*)(smem+131968);   // [2][4][68]
  float* ldsL =(float*)(smem+134144);   // [4][68]
  float* sml  =(float*)(smem+135232);   // [16]
  float* cb   =(float*)(smem+135296);   // [6][4]
  unsigned long long* sred=(unsigned long long*)(smem+135424); // [256]

  const int tid=threadIdx.x, lane=tid&63, wave=tid>>6;
  const int bid=blockIdx.x, j0=bid<<2;

  { const float* mats[5]={p.dWih1,p.dWhh0,p.hqW,p.dWhh1,p.fcW};
    _Float16* mh[5]={wih1h,whh0h,hqh2,whh1h,fch2};
    _Float16* ml[5]={wih1l,whh0l,hql2,whh1l,fcl2};
    #pragma unroll 1
    for (int m5=0;m5<5;++m5)
      for (int idx=tid; idx<4096; idx+=512){
        int r=idx>>10,k=idx&1023;
        _Float16 hi,lo; splitf(mats[m5][(j0+r)*1024+k],hi,lo);
        mh[m5][r*1032+k]=hi; ml[m5][r*1032+k]=lo;
      }
    for (int idx=tid; idx<8192; idx+=512){
      int r=idx>>11,k=idx&2047;
      _Float16 hi,lo; splitf(p.combW[(j0+r)*2048+k],hi,lo);
      combh2[r*2056+k]=hi; combl2[r*2056+k]=lo;
    }
    if (tid<4){
      cb[0*4+tid]=p.dbih1[j0+tid]; cb[1*4+tid]=p.dbhh0[j0+tid];
      cb[2*4+tid]=p.hqb[j0+tid];   cb[3*4+tid]=p.dbhh1[j0+tid];
      cb[4*4+tid]=p.combb[j0+tid]; cb[5*4+tid]=p.fcb[j0+tid];
    }
  }
  __syncthreads();
  unsigned phx = 0;

  // ---- P0: u0 = Whh0.h0_enc + bhh0 ; u1 = Whh1.h1_enc + bhh1 ----
  dmm_dual(lane,wave, p.h0h+BH,p.h0l+BH, p.h1h,p.h1l,
           whh0h,whh0l, whh1h,whh1l, ldsD);
  __syncthreads();
  if (tid<256){
    int b=tid&63, j=tid>>6, col=j0+j;
    st_f32(p.u0 + b*1024+col, ldsD[j*68+b]     + cb[1*4+j]);
    st_f32(p.u1 + b*1024+col, ldsD[272+j*68+b] + cb[3*4+j]);
  }
  ++phx; gbar(p.bar1, phx<<8);

  #pragma unroll 1
  for (int t=0; t<64; ++t){
    // ---- P1: argmax(t-1) + h0 = tanh(T0[tok] + u0) ----
    if (bid < 64){
      const int b = bid;
      if (tid<256){
        unsigned long long v=0;
        if (t>0) v = p.amax[b*256+tid];
        sred[tid]=v;
      }
      __syncthreads();
      for (int o=128;o>=1;o>>=1){
        if (tid<o){ unsigned long long x=sred[tid+o]; if (x>sred[tid]) sred[tid]=x; }
        __syncthreads();
      }
      const int tok = (t>0)? (1023 - (int)(sred[0]&0xffffffffULL)) : 0;
      int h2=tid<<1;
      float v0=tanhf(reconf(p.T0h[tok*1024+h2],  p.T0l[tok*1024+h2])   + p.u0[b*1024+h2]);
      float v1=tanhf(reconf(p.T0h[tok*1024+h2+1],p.T0l[tok*1024+h2+1]) + p.u0[b*1024+h2+1]);
      uint32_t ph_,pl_; pack2(v0,v1,ph_,pl_);
      st_u32((uint32_t*)p.dh0h + ((b*1024+h2)>>1), ph_);
      st_u32((uint32_t*)p.dh0l + ((b*1024+h2)>>1), pl_);
    }
    ++phx; gbar(p.bar1, phx<<8);

    // ---- P2: w1x = Wih1.dh0 -> h1 = tanh(w1x+bih1+u1); u0' = Whh0.dh0+bhh0 ----
    dmm_dual(lane,wave, p.dh0h,p.dh0l, p.dh0h,p.dh0l,
             wih1h,wih1l, whh0h,whh0l, ldsD);
    __syncthreads();
    if (tid<128){
      int b=tid&63, jp=tid>>6;
      float nv[2];
      #pragma unroll
      for (int d=0;d<2;++d){
        int j=(jp<<1)+d, col=j0+j;
        nv[d] = tanhf(ldsD[j*68+b] + cb[0*4+j] + p.u1[b*1024+col]);
      }
      uint32_t ph_,pl_; pack2(nv[0],nv[1],ph_,pl_);
      int c0=j0+(jp<<1);
      st_u32((uint32_t*)p.dh1h + ((b*1024+c0)>>1), ph_);
      st_u32((uint32_t*)p.dh1l + ((b*1024+c0)>>1), pl_);
      st_u32((uint32_t*)p.cath + ((b*2048+c0)>>1), ph_);
      st_u32((uint32_t*)p.catl + ((b*2048+c0)>>1), pl_);
    } else if (tid<256){
      int t2=tid-128; int b=t2&63, jp=t2>>6;
      #pragma unroll
      for (int d=0;d<2;++d){
        int j=(jp<<1)+d, col=j0+j;
        st_f32(p.u0 + b*1024+col, ldsD[272+j*68+b] + cb[1*4+j]);
      }
    }
    ++phx; gbar(p.bar1, phx<<8);

    // ---- P3: q = hq.dh1 + hqb ; u1' = Whh1.dh1 + bhh1 ----
    dmm_dual(lane,wave, p.dh1h,p.dh1l, p.dh1h,p.dh1l,
             hqh2,hql2, whh1h,whh1l, ldsD);
    __syncthreads();
    if (tid<256){
      int b=tid&63, j=tid>>6, col=j0+j;
      st_f32(p.q  + b*1024+col, ldsD[j*68+b]     + cb[2*4+j]);
      st_f32(p.u1 + b*1024+col, ldsD[272+j*68+b] + cb[3*4+j]);
    }
    ++phx; gbar(p.bar1, phx<<8);

    // ---- P4: flash attention quarter (b = bid>>2, q4 = bid&3), enc f16 ----
    {
      const int b=bid>>2, q4=bid&3, s0=q4<<7;
      const uint32_t* eb = p.enc_att + ((size_t)b*SH>>1);
      float qv[16];
      #pragma unroll
      for (int i=0;i<8;++i){
        float2 qq = *(const float2*)(p.q + b*1024 + (((i<<6)+lane)<<1));
        qv[2*i]=qq.x; qv[2*i+1]=qq.y;
      }
      float ov[16];
      #pragma unroll
      for (int i=0;i<16;++i) ov[i]=0.f;
      float mrun=-3.0e38f, lrun=0.f;
      #pragma unroll 2
      for (int si=0; si<16; ++si){
        int s = s0 + (wave<<4) + si;
        const uint32_t* ep = eb + s*512 + lane;
        float ef[16]; float partial=0.f;
        #pragma unroll
        for (int i=0;i<8;++i){
          uint32_t w2 = ep[i<<6];
          float e0=(float)__builtin_bit_cast(_Float16,(unsigned short)(w2&0xffffu));
          float e1=(float)__builtin_bit_cast(_Float16,(unsigned short)(w2>>16));
          ef[2*i]=e0; ef[2*i+1]=e1;
          partial = fmaf(e1,qv[2*i+1], fmaf(e0,qv[2*i], partial));
        }
        #pragma unroll
        for (int off=32; off; off>>=1) partial += __shfl_xor(partial, off, 64);
        if (t==63 && lane==0) st_f32(p.sc63 + b*512 + s, partial);
        float mnew=fmaxf(mrun,partial);
        float fac=__expf(mrun-mnew), w=__expf(partial-mnew);
        lrun = fmaf(lrun,fac,w);
        #pragma unroll
        for (int i=0;i<16;++i) ov[i]=fmaf(ov[i],fac,w*ef[i]);
        mrun=mnew;
      }
      if (lane==0){ sml[wave]=mrun; sml[8+wave]=lrun; }
      __syncthreads();
      float Mx=sml[0];
      #pragma unroll
      for (int w=1;w<8;++w) Mx=fmaxf(Mx,sml[w]);
      float fw=__expf(sml[wave]-Mx);
      if (wave<4){
        #pragma unroll
        for (int i=0;i<8;++i){
          int h=((i<<6)+lane)<<1;
          sbufA[wave*1032+h]  =fw*ov[2*i];
          sbufA[wave*1032+h+1]=fw*ov[2*i+1];
        }
      }
      __syncthreads();
      if (wave>=4){
        #pragma unroll
        for (int i=0;i<8;++i){
          int h=((i<<6)+lane)<<1;
          sbufA[(wave-4)*1032+h]  +=fw*ov[2*i];
          sbufA[(wave-4)*1032+h+1]+=fw*ov[2*i+1];
        }
      }
      __syncthreads();
      if (tid==0){
        float L=0.f;
        #pragma unroll
        for (int w=0;w<8;++w) L += __expf(sml[w]-Mx)*sml[8+w];
        st_f32(p.attp_ml + (b*4+q4)*2,   Mx);
        st_f32(p.attp_ml + (b*4+q4)*2+1, L);
      }
      { int h2=tid<<1;
        float o0=sbufA[h2]+sbufA[1032+h2]+sbufA[2064+h2]+sbufA[3096+h2];
        float o1=sbufA[h2+1]+sbufA[1032+h2+1]+sbufA[2064+h2+1]+sbufA[3096+h2+1];
        st_f32(p.attp_o + (b*4+q4)*1024 + h2,   o0);
        st_f32(p.attp_o + (b*4+q4)*1024 + h2+1, o1);
      }
    }
    ++phx; gbar(p.bar1, phx<<8);

    // ---- P5: combine quarters -> att into cat[:,1024:]; t=63: attn output ----
    if (bid < 64){
      const int b=bid;
      float m0=p.attp_ml[b*8+0], l0=p.attp_ml[b*8+1];
      float m1=p.attp_ml[b*8+2], l1=p.attp_ml[b*8+3];
      float m2=p.attp_ml[b*8+4], l2=p.attp_ml[b*8+5];
      float m3=p.attp_ml[b*8+6], l3=p.attp_ml[b*8+7];
      float Mx=fmaxf(fmaxf(m0,m1),fmaxf(m2,m3));
      float f0=expf(m0-Mx),f1=expf(m1-Mx),f2=expf(m2-Mx),f3=expf(m3-Mx);
      float invL=1.0f/(f0*l0+f1*l1+f2*l2+f3*l3);
      int h2=tid<<1;
      float o0=(f0*p.attp_o[(b*4+0)*1024+h2]+f1*p.attp_o[(b*4+1)*1024+h2]
               +f2*p.attp_o[(b*4+2)*1024+h2]+f3*p.attp_o[(b*4+3)*1024+h2])*invL;
      float o1=(f0*p.attp_o[(b*4+0)*1024+h2+1]+f1*p.attp_o[(b*4+1)*1024+h2+1]
               +f2*p.attp_o[(b*4+2)*1024+h2+1]+f3*p.attp_o[(b*4+3)*1024+h2+1])*invL;
      uint32_t ph_,pl_; pack2(o0,o1,ph_,pl_);
      st_u32((uint32_t*)p.cath + ((b*2048+1024+h2)>>1), ph_);
      st_u32((uint32_t*)p.catl + ((b*2048+1024+h2)>>1), pl_);
      if (t==63)
        st_f32(p.dout + OFF_ATTN + b*512 + tid, expf(p.sc63[b*512+tid]-Mx)*invL);
    }
    ++phx; gbar(p.bar1, phx<<8);

    // ---- P6: c = comb_W.[h1|att] + comb_b ----
    dmm_sk<2048>(lane,wave, p.cath, p.catl, combh2, combl2, ldsD);
    __syncthreads();
    if (tid<128){
      int b=tid&63, jp=tid>>6;
      float nv[2];
      #pragma unroll
      for (int d=0;d<2;++d){
        int j=(jp<<1)+d;
        nv[d] = ldsD[j*68+b] + ldsD[272+j*68+b] + cb[4*4+j];
      }
      uint32_t ph_,pl_; pack2(nv[0],nv[1],ph_,pl_);
      int c0=j0+(jp<<1);
      st_u32((uint32_t*)p.ch + ((b*1024+c0)>>1), ph_);
      st_u32((uint32_t*)p.cl + ((b*1024+c0)>>1), pl_);
    }
    ++phx; gbar(p.bar1, phx<<8);

    // ---- P7: logits = fc.c + fc_b -> dout + argmax partials ----
    dmm_sk<1024>(lane,wave, p.ch, p.cl, fch2, fcl2, ldsD);
    __syncthreads();
    if (tid<256){
      int b=tid&63, j=tid>>6, col=j0+j;
      float val = ldsD[j*68+b] + ldsD[272+j*68+b] + cb[5*4+j];
      st_f32(p.dout + b*65536 + t*1024 + col, val);
      ldsL[j*68+b] = val;
    }
    __syncthreads();
    if (tid<64){
      int b=tid; float best=-3.0e38f; int bi=0;
      #pragma unroll
      for (int j=0;j<4;++j){
        float v=ldsL[j*68+b];
        if (v>best){ best=v; bi=j; }
      }
      st_u64(p.amax + b*256 + bid,
             ((unsigned long long)ordf(best)<<32) | (unsigned)(1023-(j0+bi)));
    }
    ++phx; gbar(p.bar1, phx<<8);
  }

  // ---- final hidden output [2][B][H] ----
  { int idx=bid*512+tid;
    int i=idx&65535;
    float v=(idx>>16)? reconf(p.dh1h[i],p.dh1l[i]) : reconf(p.dh0h[i],p.dh0l[i]);
    st_f32(p.dout + OFF_HID + idx, v);
  }
}

// ---------------- host ----------------
extern "C" void kernel_launch(void* const* d_in, const int* in_sizes, int n_in,
                              void* d_out, int out_size, void* d_ws, size_t ws_size,
                              hipStream_t stream)
{
  (void)in_sizes; (void)n_in; (void)out_size;
  P p;
  p.x     = (const float*)d_in[0];  p.emb   = (const float*)d_in[1];
  p.eWih0 = (const float*)d_in[2];  p.eWhh0 = (const float*)d_in[3];
  p.ebih0 = (const float*)d_in[4];  p.ebhh0 = (const float*)d_in[5];
  p.dWih0 = (const float*)d_in[6];  p.dWhh0 = (const float*)d_in[7];
  p.dbih0 = (const float*)d_in[8];  p.dbhh0 = (const float*)d_in[9];
  p.eWih1 = (const float*)d_in[10]; p.eWhh1 = (const float*)d_in[11];
  p.ebih1 = (const float*)d_in[12]; p.ebhh1 = (const float*)d_in[13];
  p.dWih1 = (const float*)d_in[14]; p.dWhh1 = (const float*)d_in[15];
  p.dbih1 = (const float*)d_in[16]; p.dbhh1 = (const float*)d_in[17];
  p.hqW   = (const float*)d_in[18]; p.hqb   = (const float*)d_in[19];
  p.combW = (const float*)d_in[20]; p.combb = (const float*)d_in[21];
  p.fcW   = (const float*)d_in[22]; p.fcb   = (const float*)d_in[23];
  p.dout  = (float*)d_out;

  char* base = (char*)d_ws; size_t off = 0;
  auto alloc = [&](size_t bytes)->char*{
    char* r = base + off; off = (off + bytes + 255) & ~(size_t)255; return r;
  };
  p.enc_att = (uint32_t*)alloc(16777216ULL*4);     // 64 MB f16 enc_outs
  p.embh  = (_Float16*)alloc(1048576ULL*2); p.embl  = (_Float16*)alloc(1048576ULL*2);
  p.T0h   = (_Float16*)alloc(1048576ULL*2); p.T0l   = (_Float16*)alloc(1048576ULL*2);
  p.wih0dh= (_Float16*)alloc(1048576ULL*2); p.wih0dl= (_Float16*)alloc(1048576ULL*2);
  p.h0h   = (_Float16*)alloc(131072ULL*2);  p.h0l   = (_Float16*)alloc(131072ULL*2);
  p.h1h   = (_Float16*)alloc(131072ULL*2);  p.h1l   = (_Float16*)alloc(131072ULL*2);
  p.dh0h  = (_Float16*)alloc(65536ULL*2);   p.dh0l  = (_Float16*)alloc(65536ULL*2);
  p.dh1h  = (_Float16*)alloc(65536ULL*2);   p.dh1l  = (_Float16*)alloc(65536ULL*2);
  p.cath  = (_Float16*)alloc(131072ULL*2);  p.catl  = (_Float16*)alloc(131072ULL*2);
  p.ch    = (_Float16*)alloc(65536ULL*2);   p.cl    = (_Float16*)alloc(65536ULL*2);
  p.u0    = (float*)alloc(65536ULL*4);      p.u1    = (float*)alloc(65536ULL*4);
  p.q     = (float*)alloc(65536ULL*4);
  p.attp_o  = (float*)alloc(262144ULL*4);
  p.attp_ml = (float*)alloc(512ULL*4);
  p.sc63    = (float*)alloc(32768ULL*4);
  p.amax    = (unsigned long long*)alloc(16384ULL*8);
  { unsigned* bars = (unsigned*)alloc(512*4);
    p.bar0 = bars; p.bar1 = bars + 256; }
  if (off > ws_size) return;

  hipFuncSetAttribute(reinterpret_cast<const void*>(k_encp),
                      hipFuncAttributeMaxDynamicSharedMemorySize, ENC_LDS);
  hipFuncSetAttribute(reinterpret_cast<const void*>(k_decp),
                      hipFuncAttributeMaxDynamicSharedMemorySize, DEC_LDS);

  k_split<<<2048,256,0,stream>>>(p.emb,   p.embh,   p.embl,   1048576);
  k_split<<<2048,256,0,stream>>>(p.dWih0, p.wih0dh, p.wih0dl, 1048576);
  k_zero <<<256,256,0,stream>>>(p);
  k_t0   <<<1024,256,0,stream>>>(p);
  k_encp <<<256,512,ENC_LDS,stream>>>(p);
  k_decp <<<256,512,DEC_LDS,stream>>>(p);
}

// Round 6
// 33470.630 us; speedup vs baseline: 1.3812x; 1.1328x over previous
//
#include <hip/hip_runtime.h>
#include <stdint.h>

// ---------------------------------------------------------------------------
// Round 6: round 5's atomic-free grid barrier + REVERTED argmax partials
// (round 5 wrongly halved amax coverage to vocab cols 0-511 -> token flips).
// amax is [B][256], written by all 256 blocks (4 vocab cols each), reduced
// over 256 in P1. Everything else identical to round 5.
// ---------------------------------------------------------------------------

#define BB 64
#define SS 512
#define TT 64
#define HH 1024
#define VV 1024
#define BH 65536   // B*H
#define SH 524288  // S*H
#define OFF_HID  4194304           // B*T*V
#define OFF_ATTN 4325376           // + L*B*H

#define ENC_LDS 160864
#define DEC_LDS 137472

typedef _Float16 half8  __attribute__((ext_vector_type(8)));
typedef float    floatx4 __attribute__((ext_vector_type(4)));

#define MFMA16(a,b,c) __builtin_amdgcn_mfma_f32_16x16x32_f16(a,b,c,0,0,0)

struct P {
  const float *x, *emb;
  const float *eWih0, *eWhh0, *ebih0, *ebhh0;
  const float *dWih0, *dWhh0, *dbih0, *dbhh0;
  const float *eWih1, *eWhh1, *ebih1, *ebhh1;
  const float *dWih1, *dWhh1, *dbih1, *dbhh1;
  const float *hqW, *hqb, *combW, *combb, *fcW, *fcb;
  uint32_t* enc_att;               // [B][S][H] f16, 2 per u32
  _Float16 *embh,*embl,*T0h,*T0l;  // T0 = emb @ dWih0^T + dbih0  [V][H] pairs
  _Float16 *wih0dh,*wih0dl;
  _Float16 *h0h,*h0l,*h1h,*h1l;    // [2][B*H] parity-double-buffered enc states
  _Float16 *dh0h,*dh0l,*dh1h,*dh1l;// decoder states [B*H]
  _Float16 *cath,*catl;            // [B][2048] = [h1 | att] pairs
  _Float16 *ch,*cl;                // comb output pairs [B*H]
  float *u0,*u1,*q;                // fp32 [B*H]
  float *attp_o;                   // [B][4][H]
  float *attp_ml;                  // [B][4][2]
  float *sc63;                     // [B][S] raw scores at t=63
  unsigned long long* amax;        // [B][256] argmax partials (zeroed)
  unsigned *ea,*eg,*da,*dg;        // barrier: arrival[256*32], go[4*32] x2 sets
  float* dout;
};

// ---------------- helpers ----------------
__device__ __forceinline__ void splitf(float x, _Float16& hi, _Float16& lo){
  _Float16 h = (_Float16)x; hi = h;
  lo = (_Float16)((x - (float)h) * 2048.0f);
}
__device__ __forceinline__ float reconf(_Float16 hi, _Float16 lo){
  return fmaf((float)lo, 1.0f/2048.0f, (float)hi);
}
__device__ __forceinline__ unsigned ordf(float f){
  unsigned u = __float_as_uint(f);
  return (u & 0x80000000u) ? ~u : (u | 0x80000000u);
}
__device__ __forceinline__ void pack2(float v0, float v1, uint32_t& ph, uint32_t& pl){
  _Float16 h0,l0,h1,l1; splitf(v0,h0,l0); splitf(v1,h1,l1);
  ph = (uint32_t)__builtin_bit_cast(unsigned short,h0)
     | ((uint32_t)__builtin_bit_cast(unsigned short,h1) << 16);
  pl = (uint32_t)__builtin_bit_cast(unsigned short,l0)
     | ((uint32_t)__builtin_bit_cast(unsigned short,l1) << 16);
}
// system-scope stores/loads: bypass L1/L2, coherent at L3
__device__ __forceinline__ void st_u32(uint32_t* p2, uint32_t v){
  __hip_atomic_store(p2, v, __ATOMIC_RELAXED, __HIP_MEMORY_SCOPE_SYSTEM);
}
__device__ __forceinline__ void st_f32(float* p2, float v){
  __hip_atomic_store(p2, v, __ATOMIC_RELAXED, __HIP_MEMORY_SCOPE_SYSTEM);
}
__device__ __forceinline__ void st_u64(unsigned long long* p2, unsigned long long v){
  __hip_atomic_store(p2, v, __ATOMIC_RELAXED, __HIP_MEMORY_SCOPE_SYSTEM);
}
__device__ __forceinline__ unsigned ldsys(const unsigned* pp){
  return __hip_atomic_load(pp, __ATOMIC_RELAXED, __HIP_MEMORY_SCOPE_SYSTEM);
}

// Atomic-free grid barrier: per-block private arrival lines (parallel system
// stores, no RMW serialization); block 0 wave 0 gathers 256 flags with 4
// strided 64-lane loads, broadcasts 4 go-flag copies; others poll only their
// go copy. __syncthreads on entry drains vmem stores; acquire-only fence on
// exit invalidates L1/L2 (no writeback needed: cross-block data is system-
// scope write-through).
__device__ __forceinline__ void gbar(unsigned* arr, unsigned* go, unsigned e){
  __syncthreads();
  const int tid = threadIdx.x, bid = blockIdx.x;
  if (tid == 0)
    __hip_atomic_store(arr + bid*32, e, __ATOMIC_RELAXED, __HIP_MEMORY_SCOPE_SYSTEM);
  if (bid == 0){
    if (tid < 64){
      for (;;){
        unsigned v0 = ldsys(arr +  tid      *32);
        unsigned v1 = ldsys(arr + (tid+ 64) *32);
        unsigned v2 = ldsys(arr + (tid+128) *32);
        unsigned v3 = ldsys(arr + (tid+192) *32);
        bool ok = (v0>=e) & (v1>=e) & (v2>=e) & (v3>=e);
        if (__ballot(ok) == ~0ull) break;
        __builtin_amdgcn_s_sleep(1);
      }
      if (tid == 0){
        __hip_atomic_store(go+0,  e, __ATOMIC_RELAXED, __HIP_MEMORY_SCOPE_SYSTEM);
        __hip_atomic_store(go+32, e, __ATOMIC_RELAXED, __HIP_MEMORY_SCOPE_SYSTEM);
        __hip_atomic_store(go+64, e, __ATOMIC_RELAXED, __HIP_MEMORY_SCOPE_SYSTEM);
        __hip_atomic_store(go+96, e, __ATOMIC_RELAXED, __HIP_MEMORY_SCOPE_SYSTEM);
      }
    }
  } else {
    if (tid == 0){
      while (ldsys(go + (bid&3)*32) < e) __builtin_amdgcn_s_sleep(2);
    }
  }
  __syncthreads();
  __builtin_amdgcn_fence(__ATOMIC_ACQUIRE, "agent");   // inv L1+L2, no wbl2
}

// ---------------- split-precision GEMM core (k_t0 only) ----------------
template<int NT, int KH, bool SPLIT>
__device__ __forceinline__ void gemm_core(
    const _Float16* __restrict__ Ah0, const _Float16* __restrict__ Al0,
    const _Float16* __restrict__ Ah1, const _Float16* __restrict__ Al1,
    int sA,
    const _Float16* __restrict__ Wh, const _Float16* __restrict__ Wl,
    int nrows, _Float16* ldsW, float* accOut)
{
  const int tid = threadIdx.x, lane = tid & 63, wave = tid >> 6;
  const int mA = (wave<<4) + (lane & 15);
  const int kb = ((lane>>4) << 3);
  const int wstride = KH << 10;
  floatx4 aH[NT], aM1[NT], aM2[NT];
  int ne[NT];
  const _Float16* bh_base[NT];
  const _Float16* bl_base[NT];
  #pragma unroll
  for (int nt=0; nt<NT; ++nt){
    int nn = (lane & 15) + (nt<<4);
    ne[nt] = nn < nrows ? nn : nrows - 1;
    bh_base[nt] = ldsW + ne[nt]*1032 + kb;
    aH[nt]  = floatx4{0.f,0.f,0.f,0.f};
    aM1[nt] = floatx4{0.f,0.f,0.f,0.f};
    aM2[nt] = floatx4{0.f,0.f,0.f,0.f};
  }
  #pragma unroll
  for (int kh=0; kh<KH; ++kh){
    __syncthreads();
    const int iters = (nrows*128 + 255) >> 8;
    for (int it=0; it<iters; ++it){
      int idx = tid + (it<<8);
      int row = idx >> 7, col = (idx & 127) << 3;
      if (row < nrows)
        *(half8*)(ldsW + row*1032 + col) =
            *(const half8*)(Wh + row*wstride + (kh<<10) + col);
    }
    __syncthreads();
    const _Float16* ah_p = ((KH==2 && kh==1) ? Ah1 : Ah0) + mA*sA + kb;
    const _Float16* al_p = ((KH==2 && kh==1) ? Al1 : Al0) + mA*sA + kb;
    #pragma unroll
    for (int nt=0; nt<NT; ++nt) bl_base[nt] = Wl + ne[nt]*wstride + (kh<<10) + kb;
    #pragma unroll 4
    for (int ks=0; ks<32; ++ks){
      half8 ah = *(const half8*)(ah_p + (ks<<5));
      half8 al = *(const half8*)(al_p + (ks<<5));
      #pragma unroll
      for (int nt=0; nt<NT; ++nt){
        half8 bh = *(const half8*)(bh_base[nt] + (ks<<5));
        half8 bl = *(const half8*)(bl_base[nt] + (ks<<5));
        aH[nt]  = MFMA16(ah, bh, aH[nt]);
        aM1[nt] = MFMA16(ah, bl, aM1[nt]);
        aM2[nt] = MFMA16(al, bh, aM2[nt]);
      }
    }
  }
  #pragma unroll
  for (int nt=0; nt<NT; ++nt)
    #pragma unroll
    for (int r=0;r<4;++r)
      accOut[nt*4 + r] = aH[nt][r] + (aM1[nt][r] + aM2[nt][r]) * (1.f/2048.f);
}

// ---------------- prologue kernels ----------------
__global__ __launch_bounds__(256) void k_split(const float* __restrict__ src,
                                               _Float16* dh, _Float16* dl, int n){
  for (int i = blockIdx.x*256 + threadIdx.x; i < n; i += gridDim.x*256){
    _Float16 hi,lo; splitf(src[i],hi,lo); dh[i]=hi; dl[i]=lo;
  }
}
__global__ __launch_bounds__(256) void k_zero(P p){
  int i = blockIdx.x*256 + threadIdx.x;   // grid 256 -> 65536 threads
  p.h1h[i] = (_Float16)0.f; p.h1l[i] = (_Float16)0.f;           // h1 parity 0
  p.h0h[BH + i] = (_Float16)0.f; p.h0l[BH + i] = (_Float16)0.f; // h0 parity 1
  if (i < 16640) p.ea[i] = 0u;            // both barrier sets (contiguous)
  if (i < 16384) p.amax[i] = 0ULL;        // B x 256 argmax partials
}
// T0[v][j] = emb[v] . dWih0[j] + dbih0[j]
__global__ __launch_bounds__(256) void k_t0(P p){
  __shared__ _Float16 ldsW[16*1032];
  const int ns = blockIdx.x & 63, mc = blockIdx.x >> 6;
  float acc[4];
  gemm_core<1,1,false>(p.embh + mc*65536, p.embl + mc*65536, nullptr, nullptr, 1024,
                       p.wih0dh + ns*16*1024, p.wih0dl + ns*16*1024, 16, ldsW, acc);
  const int lane = threadIdx.x & 63, wave = threadIdx.x >> 6;
  const int n = lane & 15, col = (ns<<4) + n;
  const float bv = p.dbih0[col];
  #pragma unroll
  for (int r=0;r<4;++r){
    int v = mc*64 + (wave<<4) + ((lane>>4)<<2) + r;
    _Float16 hi,lo; splitf(acc[r] + bv, hi, lo);
    p.T0h[v*1024 + col] = hi; p.T0l[v*1024 + col] = lo;
  }
}

// ---------------- persistent encoder ----------------
// 256 blocks x 512 thr; block owns 4 output cols j of BOTH layers.
__global__ __launch_bounds__(512,1) void k_encp(P p){
  extern __shared__ char smem[];
  _Float16* W0h = (_Float16*)smem;       // 12*1032
  _Float16* W0l = W0h + 12384;
  _Float16* W1h = W0l + 12384;           // 12*2056
  _Float16* W1l = W1h + 24672;
  float* ldsA = (float*)(smem + 148224); // [36][68]
  float* ldsC = ldsA + 2448;             // [12][6]
  float* ldsH0 = (float*)(smem + 158304);// [64][5] f32 own-col h cache
  float* ldsH1 = (float*)(smem + 159584);// [64][5]
  const int tid = threadIdx.x, lane = tid & 63, wave = tid >> 6;
  const int bid = blockIdx.x, j0 = bid << 2;

  for (int idx=tid; idx<12*1024; idx+=512){
    int r=idx>>10, k=idx&1023;
    int grow=(r>>2)*1024 + j0 + (r&3);
    _Float16 hi,lo; splitf(p.eWhh0[grow*1024+k],hi,lo);
    W0h[r*1032+k]=hi; W0l[r*1032+k]=lo;
  }
  for (int idx=tid; idx<12*2048; idx+=512){
    int r=idx>>11, k=idx&2047;
    int grow=(r>>2)*1024 + j0 + (r&3);
    float v = (k<1024)? p.eWhh1[grow*1024+k] : p.eWih1[grow*1024+(k-1024)];
    _Float16 hi,lo; splitf(v,hi,lo);
    W1h[r*2056+k]=hi; W1l[r*2056+k]=lo;
  }
  if (tid<12){
    int grow=(tid>>2)*1024 + j0 + (tid&3);
    ldsC[tid*6+0]=p.eWih0[grow*2+0]; ldsC[tid*6+1]=p.eWih0[grow*2+1];
    ldsC[tid*6+2]=p.ebih0[grow];     ldsC[tid*6+3]=p.ebhh0[grow];
    ldsC[tid*6+4]=p.ebih1[grow];     ldsC[tid*6+5]=p.ebhh1[grow];
  }
  if (tid < 256){
    ldsH0[(tid&63)*5 + (tid>>6)] = 0.f;
    ldsH1[(tid&63)*5 + (tid>>6)] = 0.f;
  }
  __syncthreads();

  const int ln15 = lane & 15, kb = (lane >> 4) << 3;
  const bool isl1 = wave >= 4;
  const int mt = wave & 3;
  const int brow = (ln15 < 12) ? ln15 : 11;
  const int mrow = (mt<<4) + ln15;
  const int msub = (mt<<4) + ((lane>>4)<<2);

  #pragma unroll 1
  for (int e=0; e<=512; ++e){
    const int cur=e&1, prv=cur^1;
    float xv0=0.f, xv1=0.f;
    if (tid < 128 && e < 512){
      const int b2 = tid & 63;
      xv0 = p.x[b2*1024 + e]; xv1 = p.x[b2*1024 + 512 + e];
    }
    if (!isl1){
      if (e < 512){
        const _Float16* ah = p.h0h + prv*BH + mrow*1024 + kb;
        const _Float16* al = p.h0l + prv*BH + mrow*1024 + kb;
        const _Float16* bh = W0h + brow*1032 + kb;
        const _Float16* bl = W0l + brow*1032 + kb;
        floatx4 H{0,0,0,0},M{0,0,0,0},N{0,0,0,0};
        #pragma unroll 16
        for (int ks=0;ks<32;++ks){
          int off=ks<<5;
          half8 A=*(const half8*)(ah+off), Alo=*(const half8*)(al+off);
          half8 B=*(const half8*)(bh+off), Blo=*(const half8*)(bl+off);
          H=MFMA16(A,B,H); M=MFMA16(A,Blo,M); N=MFMA16(Alo,B,N);
        }
        if (ln15<12){
          #pragma unroll
          for (int r=0;r<4;++r)
            ldsA[ln15*68 + msub + r] = H[r] + (M[r]+N[r])*(1.f/2048.f);
        }
      }
    } else {
      if (e >= 1){
        const _Float16* a1h = p.h1h + prv*BH + mrow*1024 + kb;
        const _Float16* a1l = p.h1l + prv*BH + mrow*1024 + kb;
        const _Float16* a0h = p.h0h + prv*BH + mrow*1024 + kb;
        const _Float16* a0l = p.h0l + prv*BH + mrow*1024 + kb;
        const _Float16* bh = W1h + brow*2056 + kb;
        const _Float16* bl = W1l + brow*2056 + kb;
        floatx4 H1{0,0,0,0},M1{0,0,0,0},N1{0,0,0,0};
        floatx4 H2{0,0,0,0},M2{0,0,0,0},N2{0,0,0,0};
        #pragma unroll 8
        for (int ks=0;ks<32;++ks){
          int off=ks<<5;
          half8 A=*(const half8*)(a1h+off), Alo=*(const half8*)(a1l+off);
          half8 B=*(const half8*)(bh+off), Blo=*(const half8*)(bl+off);
          H1=MFMA16(A,B,H1); M1=MFMA16(A,Blo,M1); N1=MFMA16(Alo,B,N1);
        }
        #pragma unroll 8
        for (int ks=0;ks<32;++ks){
          int off=ks<<5;
          half8 A=*(const half8*)(a0h+off), Alo=*(const half8*)(a0l+off);
          half8 B=*(const half8*)(bh+1024+off), Blo=*(const half8*)(bl+1024+off);
          H2=MFMA16(A,B,H2); M2=MFMA16(A,Blo,M2); N2=MFMA16(Alo,B,N2);
        }
        if (ln15<12){
          #pragma unroll
          for (int r=0;r<4;++r){
            ldsA[(12+ln15)*68 + msub + r] = H1[r] + (M1[r]+N1[r])*(1.f/2048.f);
            ldsA[(24+ln15)*68 + msub + r] = H2[r] + (M2[r]+N2[r])*(1.f/2048.f);
          }
        }
      }
    }
    __syncthreads();
    if (tid < 256){
      const bool l1t = tid >= 128;
      const int b = tid & 63, jp = (tid>>6) & 1;
      const int c0 = j0 + (jp<<1);
      if (!l1t && e < 512){
        float nv[2];
        #pragma unroll
        for (int d=0; d<2; ++d){
          int jj=(jp<<1)+d, r0=jj, r1=4+jj, r2=8+jj;
          float hr = ldsA[r0*68+b] + ldsC[r0*6+3];
          float hz = ldsA[r1*68+b] + ldsC[r1*6+3];
          float hn = ldsA[r2*68+b] + ldsC[r2*6+3];
          float xr = fmaf(xv0, ldsC[r0*6+0], fmaf(xv1, ldsC[r0*6+1], ldsC[r0*6+2]));
          float xz = fmaf(xv0, ldsC[r1*6+0], fmaf(xv1, ldsC[r1*6+1], ldsC[r1*6+2]));
          float xn = fmaf(xv0, ldsC[r2*6+0], fmaf(xv1, ldsC[r2*6+1], ldsC[r2*6+2]));
          float rg = 1.0f/(1.0f + expf(-(xr+hr)));
          float zg = 1.0f/(1.0f + expf(-(xz+hz)));
          float ng = tanhf(xn + rg*hn);
          float hold = ldsH0[b*5+jj];
          nv[d] = (1.0f - zg)*ng + zg*hold;
          ldsH0[b*5+jj] = nv[d];
        }
        uint32_t ph_,pl_; pack2(nv[0],nv[1],ph_,pl_);
        st_u32((uint32_t*)(p.h0h + cur*BH) + ((b*1024+c0)>>1), ph_);
        st_u32((uint32_t*)(p.h0l + cur*BH) + ((b*1024+c0)>>1), pl_);
      } else if (l1t && e >= 1){
        const int t = e-1;
        float nv[2];
        #pragma unroll
        for (int d=0; d<2; ++d){
          int jj=(jp<<1)+d, r0=jj, r1=4+jj, r2=8+jj;
          float hr = ldsA[(12+r0)*68+b] + ldsC[r0*6+5];
          float hz = ldsA[(12+r1)*68+b] + ldsC[r1*6+5];
          float hn = ldsA[(12+r2)*68+b] + ldsC[r2*6+5];
          float xr = ldsA[(24+r0)*68+b] + ldsC[r0*6+4];
          float xz = ldsA[(24+r1)*68+b] + ldsC[r1*6+4];
          float xn = ldsA[(24+r2)*68+b] + ldsC[r2*6+4];
          float rg = 1.0f/(1.0f + expf(-(xr+hr)));
          float zg = 1.0f/(1.0f + expf(-(xz+hz)));
          float ng = tanhf(xn + rg*hn);
          float hold = ldsH1[b*5+jj];
          nv[d] = (1.0f - zg)*ng + zg*hold;
          ldsH1[b*5+jj] = nv[d];
        }
        uint32_t ph_,pl_; pack2(nv[0],nv[1],ph_,pl_);
        st_u32((uint32_t*)(p.h1h + cur*BH) + ((b*1024+c0)>>1), ph_);
        st_u32((uint32_t*)(p.h1l + cur*BH) + ((b*1024+c0)>>1), pl_);
        _Float16 e0=(_Float16)nv[0], e1=(_Float16)nv[1];
        uint32_t pe = (uint32_t)__builtin_bit_cast(unsigned short,e0)
                    | ((uint32_t)__builtin_bit_cast(unsigned short,e1) << 16);
        st_u32(p.enc_att + (((size_t)b*SH + t*1024 + c0)>>1), pe);
      }
    }
    gbar(p.ea, p.eg, (unsigned)(e+1));
  }
}

// ---------------- decoder GEMM helpers (weights in LDS) ----------------
__device__ __forceinline__ void dmm_dual(int lane, int wave,
    const _Float16* A0h, const _Float16* A0l,
    const _Float16* A1h, const _Float16* A1l,
    const _Float16* W0h_, const _Float16* W0l_,
    const _Float16* W1h_, const _Float16* W1l_,
    float* ldsD)
{
  const int mt = wave>>1, sel = wave&1;
  const int ln15 = lane&15, kb = (lane>>4)<<3, n = ln15&3;
  const _Float16* ah = (sel? A1h:A0h) + ((mt<<4)+ln15)*1024 + kb;
  const _Float16* al = (sel? A1l:A0l) + ((mt<<4)+ln15)*1024 + kb;
  const _Float16* bh = (sel? W1h_:W0h_) + n*1032 + kb;
  const _Float16* bl = (sel? W1l_:W0l_) + n*1032 + kb;
  floatx4 H{0,0,0,0},M{0,0,0,0},N{0,0,0,0};
  #pragma unroll 8
  for (int ks=0;ks<32;++ks){
    int off=ks<<5;
    half8 A=*(const half8*)(ah+off), Alo=*(const half8*)(al+off);
    half8 B=*(const half8*)(bh+off), Blo=*(const half8*)(bl+off);
    H=MFMA16(A,B,H); M=MFMA16(A,Blo,M); N=MFMA16(Alo,B,N);
  }
  if (ln15 < 4){
    #pragma unroll
    for (int r=0;r<4;++r)
      ldsD[sel*272 + n*68 + (mt<<4)+((lane>>4)<<2)+r] = H[r]+(M[r]+N[r])*(1.f/2048.f);
  }
}
template<int K>
__device__ __forceinline__ void dmm_sk(int lane, int wave,
    const _Float16* Ah, const _Float16* Al,
    const _Float16* Wh_, const _Float16* Wl_,
    float* ldsD)
{
  const int mt = wave>>1, kg = wave&1;
  const int ln15 = lane&15, kb = (lane>>4)<<3, n = ln15&3;
  const int k0 = kg*(K/2);
  const _Float16* ah = Ah + ((mt<<4)+ln15)*K + k0 + kb;
  const _Float16* al = Al + ((mt<<4)+ln15)*K + k0 + kb;
  const _Float16* bh = Wh_ + n*(K+8) + k0 + kb;
  const _Float16* bl = Wl_ + n*(K+8) + k0 + kb;
  floatx4 H{0,0,0,0},M{0,0,0,0},N{0,0,0,0};
  #pragma unroll 8
  for (int ks=0;ks<K/64;++ks){
    int off=ks<<5;
    half8 A=*(const half8*)(ah+off), Alo=*(const half8*)(al+off);
    half8 B=*(const half8*)(bh+off), Blo=*(const half8*)(bl+off);
    H=MFMA16(A,B,H); M=MFMA16(A,Blo,M); N=MFMA16(Alo,B,N);
  }
  if (ln15 < 4){
    #pragma unroll
    for (int r=0;r<4;++r)
      ldsD[kg*272 + n*68 + (mt<<4)+((lane>>4)<<2)+r] = H[r]+(M[r]+N[r])*(1.f/2048.f);
  }
}

// ---------------- persistent decoder ----------------
__global__ __launch_bounds__(512,1) void k_decp(P p){
  extern __shared__ char smem[];
  _Float16* wih1h=(_Float16*)smem;      _Float16* wih1l=wih1h+4128;
  _Float16* whh0h=wih1l+4128;           _Float16* whh0l=whh0h+4128;
  _Float16* hqh2 =whh0l+4128;           _Float16* hql2 =hqh2+4128;
  _Float16* whh1h=hql2+4128;            _Float16* whh1l=whh1h+4128;
  _Float16* fch2 =whh1l+4128;           _Float16* fcl2 =fch2+4128;
  _Float16* combh2=fcl2+4128;           _Float16* combl2=combh2+8224;
  float* sbufA=(float*)(smem+115456);   // [4][1032]
  float* ldsD =(float*)(smem+131968);   // [2][4][68]
  float* ldsL =(float*)(smem+134144);   // [4][68]
  float* sml  =(float*)(smem+135232);   // [16]
  float* cb   =(float*)(smem+135296);   // [6][4]
  unsigned long long* sred=(unsigned long long*)(smem+135424); // [256]

  const int tid=threadIdx.x, lane=tid&63, wave=tid>>6;
  const int bid=blockIdx.x, j0=bid<<2;

  { const float* mats[5]={p.dWih1,p.dWhh0,p.hqW,p.dWhh1,p.fcW};
    _Float16* mh[5]={wih1h,whh0h,hqh2,whh1h,fch2};
    _Float16* ml[5]={wih1l,whh0l,hql2,whh1l,fcl2};
    #pragma unroll 1
    for (int m5=0;m5<5;++m5)
      for (int idx=tid; idx<4096; idx+=512){
        int r=idx>>10,k=idx&1023;
        _Float16 hi,lo; splitf(mats[m5][(j0+r)*1024+k],hi,lo);
        mh[m5][r*1032+k]=hi; ml[m5][r*1032+k]=lo;
      }
    for (int idx=tid; idx<8192; idx+=512){
      int r=idx>>11,k=idx&2047;
      _Float16 hi,lo; splitf(p.combW[(j0+r)*2048+k],hi,lo);
      combh2[r*2056+k]=hi; combl2[r*2056+k]=lo;
    }
    if (tid<4){
      cb[0*4+tid]=p.dbih1[j0+tid]; cb[1*4+tid]=p.dbhh0[j0+tid];
      cb[2*4+tid]=p.hqb[j0+tid];   cb[3*4+tid]=p.dbhh1[j0+tid];
      cb[4*4+tid]=p.combb[j0+tid]; cb[5*4+tid]=p.fcb[j0+tid];
    }
  }
  __syncthreads();
  unsigned phx = 0;

  // ---- P0: u0 = Whh0.h0_enc + bhh0 ; u1 = Whh1.h1_enc + bhh1 ----
  dmm_dual(lane,wave, p.h0h+BH,p.h0l+BH, p.h1h,p.h1l,
           whh0h,whh0l, whh1h,whh1l, ldsD);
  __syncthreads();
  if (tid<256){
    int b=tid&63, j=tid>>6, col=j0+j;
    st_f32(p.u0 + b*1024+col, ldsD[j*68+b]     + cb[1*4+j]);
    st_f32(p.u1 + b*1024+col, ldsD[272+j*68+b] + cb[3*4+j]);
  }
  ++phx; gbar(p.da, p.dg, phx);

  #pragma unroll 1
  for (int t=0; t<64; ++t){
    // ---- P1: argmax(t-1) + h0 = tanh(T0[tok] + u0) ----
    if (bid < 64){
      const int b = bid;
      if (tid<256){
        unsigned long long v=0;
        if (t>0) v = p.amax[b*256+tid];
        sred[tid]=v;
      }
      __syncthreads();
      for (int o=128;o>=1;o>>=1){
        if (tid<o){ unsigned long long x=sred[tid+o]; if (x>sred[tid]) sred[tid]=x; }
        __syncthreads();
      }
      const int tok = (t>0)? (1023 - (int)(sred[0]&0xffffffffULL)) : 0;
      int h2=tid<<1;
      float v0=tanhf(reconf(p.T0h[tok*1024+h2],  p.T0l[tok*1024+h2])   + p.u0[b*1024+h2]);
      float v1=tanhf(reconf(p.T0h[tok*1024+h2+1],p.T0l[tok*1024+h2+1]) + p.u0[b*1024+h2+1]);
      uint32_t ph_,pl_; pack2(v0,v1,ph_,pl_);
      st_u32((uint32_t*)p.dh0h + ((b*1024+h2)>>1), ph_);
      st_u32((uint32_t*)p.dh0l + ((b*1024+h2)>>1), pl_);
    }
    ++phx; gbar(p.da, p.dg, phx);

    // ---- P2: w1x = Wih1.dh0 -> h1 = tanh(w1x+bih1+u1); u0' = Whh0.dh0+bhh0 ----
    dmm_dual(lane,wave, p.dh0h,p.dh0l, p.dh0h,p.dh0l,
             wih1h,wih1l, whh0h,whh0l, ldsD);
    __syncthreads();
    if (tid<128){
      int b=tid&63, jp=tid>>6;
      float nv[2];
      #pragma unroll
      for (int d=0;d<2;++d){
        int j=(jp<<1)+d, col=j0+j;
        nv[d] = tanhf(ldsD[j*68+b] + cb[0*4+j] + p.u1[b*1024+col]);
      }
      uint32_t ph_,pl_; pack2(nv[0],nv[1],ph_,pl_);
      int c0=j0+(jp<<1);
      st_u32((uint32_t*)p.dh1h + ((b*1024+c0)>>1), ph_);
      st_u32((uint32_t*)p.dh1l + ((b*1024+c0)>>1), pl_);
      st_u32((uint32_t*)p.cath + ((b*2048+c0)>>1), ph_);
      st_u32((uint32_t*)p.catl + ((b*2048+c0)>>1), pl_);
    } else if (tid<256){
      int t2=tid-128; int b=t2&63, jp=t2>>6;
      #pragma unroll
      for (int d=0;d<2;++d){
        int j=(jp<<1)+d, col=j0+j;
        st_f32(p.u0 + b*1024+col, ldsD[272+j*68+b] + cb[1*4+j]);
      }
    }
    ++phx; gbar(p.da, p.dg, phx);

    // ---- P3: q = hq.dh1 + hqb ; u1' = Whh1.dh1 + bhh1 ----
    dmm_dual(lane,wave, p.dh1h,p.dh1l, p.dh1h,p.dh1l,
             hqh2,hql2, whh1h,whh1l, ldsD);
    __syncthreads();
    if (tid<256){
      int b=tid&63, j=tid>>6, col=j0+j;
      st_f32(p.q  + b*1024+col, ldsD[j*68+b]     + cb[2*4+j]);
      st_f32(p.u1 + b*1024+col, ldsD[272+j*68+b] + cb[3*4+j]);
    }
    ++phx; gbar(p.da, p.dg, phx);

    // ---- P4: flash attention quarter (b = bid>>2, q4 = bid&3), enc f16 ----
    {
      const int b=bid>>2, q4=bid&3, s0=q4<<7;
      const uint32_t* eb = p.enc_att + ((size_t)b*SH>>1);
      float qv[16];
      #pragma unroll
      for (int i=0;i<8;++i){
        float2 qq = *(const float2*)(p.q + b*1024 + (((i<<6)+lane)<<1));
        qv[2*i]=qq.x; qv[2*i+1]=qq.y;
      }
      float ov[16];
      #pragma unroll
      for (int i=0;i<16;++i) ov[i]=0.f;
      float mrun=-3.0e38f, lrun=0.f;
      #pragma unroll 2
      for (int si=0; si<16; ++si){
        int s = s0 + (wave<<4) + si;
        const uint32_t* ep = eb + s*512 + lane;
        float ef[16]; float partial=0.f;
        #pragma unroll
        for (int i=0;i<8;++i){
          uint32_t w2 = ep[i<<6];
          float e0=(float)__builtin_bit_cast(_Float16,(unsigned short)(w2&0xffffu));
          float e1=(float)__builtin_bit_cast(_Float16,(unsigned short)(w2>>16));
          ef[2*i]=e0; ef[2*i+1]=e1;
          partial = fmaf(e1,qv[2*i+1], fmaf(e0,qv[2*i], partial));
        }
        #pragma unroll
        for (int off=32; off; off>>=1) partial += __shfl_xor(partial, off, 64);
        if (t==63 && lane==0) st_f32(p.sc63 + b*512 + s, partial);
        float mnew=fmaxf(mrun,partial);
        float fac=__expf(mrun-mnew), w=__expf(partial-mnew);
        lrun = fmaf(lrun,fac,w);
        #pragma unroll
        for (int i=0;i<16;++i) ov[i]=fmaf(ov[i],fac,w*ef[i]);
        mrun=mnew;
      }
      if (lane==0){ sml[wave]=mrun; sml[8+wave]=lrun; }
      __syncthreads();
      float Mx=sml[0];
      #pragma unroll
      for (int w=1;w<8;++w) Mx=fmaxf(Mx,sml[w]);
      float fw=__expf(sml[wave]-Mx);
      if (wave<4){
        #pragma unroll
        for (int i=0;i<8;++i){
          int h=((i<<6)+lane)<<1;
          sbufA[wave*1032+h]  =fw*ov[2*i];
          sbufA[wave*1032+h+1]=fw*ov[2*i+1];
        }
      }
      __syncthreads();
      if (wave>=4){
        #pragma unroll
        for (int i=0;i<8;++i){
          int h=((i<<6)+lane)<<1;
          sbufA[(wave-4)*1032+h]  +=fw*ov[2*i];
          sbufA[(wave-4)*1032+h+1]+=fw*ov[2*i+1];
        }
      }
      __syncthreads();
      if (tid==0){
        float L=0.f;
        #pragma unroll
        for (int w=0;w<8;++w) L += __expf(sml[w]-Mx)*sml[8+w];
        st_f32(p.attp_ml + (b*4+q4)*2,   Mx);
        st_f32(p.attp_ml + (b*4+q4)*2+1, L);
      }
      { int h2=tid<<1;
        float o0=sbufA[h2]+sbufA[1032+h2]+sbufA[2064+h2]+sbufA[3096+h2];
        float o1=sbufA[h2+1]+sbufA[1032+h2+1]+sbufA[2064+h2+1]+sbufA[3096+h2+1];
        st_f32(p.attp_o + (b*4+q4)*1024 + h2,   o0);
        st_f32(p.attp_o + (b*4+q4)*1024 + h2+1, o1);
      }
    }
    ++phx; gbar(p.da, p.dg, phx);

    // ---- P5: combine quarters -> att into cat[:,1024:]; t=63: attn output ----
    if (bid < 64){
      const int b=bid;
      float m0=p.attp_ml[b*8+0], l0=p.attp_ml[b*8+1];
      float m1=p.attp_ml[b*8+2], l1=p.attp_ml[b*8+3];
      float m2=p.attp_ml[b*8+4], l2=p.attp_ml[b*8+5];
      float m3=p.attp_ml[b*8+6], l3=p.attp_ml[b*8+7];
      float Mx=fmaxf(fmaxf(m0,m1),fmaxf(m2,m3));
      float f0=expf(m0-Mx),f1=expf(m1-Mx),f2=expf(m2-Mx),f3=expf(m3-Mx);
      float invL=1.0f/(f0*l0+f1*l1+f2*l2+f3*l3);
      int h2=tid<<1;
      float o0=(f0*p.attp_o[(b*4+0)*1024+h2]+f1*p.attp_o[(b*4+1)*1024+h2]
               +f2*p.attp_o[(b*4+2)*1024+h2]+f3*p.attp_o[(b*4+3)*1024+h2])*invL;
      float o1=(f0*p.attp_o[(b*4+0)*1024+h2+1]+f1*p.attp_o[(b*4+1)*1024+h2+1]
               +f2*p.attp_o[(b*4+2)*1024+h2+1]+f3*p.attp_o[(b*4+3)*1024+h2+1])*invL;
      uint32_t ph_,pl_; pack2(o0,o1,ph_,pl_);
      st_u32((uint32_t*)p.cath + ((b*2048+1024+h2)>>1), ph_);
      st_u32((uint32_t*)p.catl + ((b*2048+1024+h2)>>1), pl_);
      if (t==63)
        st_f32(p.dout + OFF_ATTN + b*512 + tid, expf(p.sc63[b*512+tid]-Mx)*invL);
    }
    ++phx; gbar(p.da, p.dg, phx);

    // ---- P6: c = comb_W.[h1|att] + comb_b ----
    dmm_sk<2048>(lane,wave, p.cath, p.catl, combh2, combl2, ldsD);
    __syncthreads();
    if (tid<128){
      int b=tid&63, jp=tid>>6;
      float nv[2];
      #pragma unroll
      for (int d=0;d<2;++d){
        int j=(jp<<1)+d;
        nv[d] = ldsD[j*68+b] + ldsD[272+j*68+b] + cb[4*4+j];
      }
      uint32_t ph_,pl_; pack2(nv[0],nv[1],ph_,pl_);
      int c0=j0+(jp<<1);
      st_u32((uint32_t*)p.ch + ((b*1024+c0)>>1), ph_);
      st_u32((uint32_t*)p.cl + ((b*1024+c0)>>1), pl_);
    }
    ++phx; gbar(p.da, p.dg, phx);

    // ---- P7: logits = fc.c + fc_b -> dout + argmax partials ----
    dmm_sk<1024>(lane,wave, p.ch, p.cl, fch2, fcl2, ldsD);
    __syncthreads();
    if (tid<256){
      int b=tid&63, j=tid>>6, col=j0+j;
      float val = ldsD[j*68+b] + ldsD[272+j*68+b] + cb[5*4+j];
      st_f32(p.dout + b*65536 + t*1024 + col, val);
      ldsL[j*68+b] = val;
    }
    __syncthreads();
    if (tid<64){
      int b=tid; float best=-3.0e38f; int bi=0;
      #pragma unroll
      for (int j=0;j<4;++j){
        float v=ldsL[j*68+b];
        if (v>best){ best=v; bi=j; }
      }
      st_u64(p.amax + b*256 + bid,
             ((unsigned long long)ordf(best)<<32) | (unsigned)(1023-(j0+bi)));
    }
    ++phx; gbar(p.da, p.dg, phx);
  }

  // ---- final hidden output [2][B][H] ----
  { int idx=bid*512+tid;
    int i=idx&65535;
    float v=(idx>>16)? reconf(p.dh1h[i],p.dh1l[i]) : reconf(p.dh0h[i],p.dh0l[i]);
    st_f32(p.dout + OFF_HID + idx, v);
  }
}

// ---------------- host ----------------
extern "C" void kernel_launch(void* const* d_in, const int* in_sizes, int n_in,
                              void* d_out, int out_size, void* d_ws, size_t ws_size,
                              hipStream_t stream)
{
  (void)in_sizes; (void)n_in; (void)out_size;
  P p;
  p.x     = (const float*)d_in[0];  p.emb   = (const float*)d_in[1];
  p.eWih0 = (const float*)d_in[2];  p.eWhh0 = (const float*)d_in[3];
  p.ebih0 = (const float*)d_in[4];  p.ebhh0 = (const float*)d_in[5];
  p.dWih0 = (const float*)d_in[6];  p.dWhh0 = (const float*)d_in[7];
  p.dbih0 = (const float*)d_in[8];  p.dbhh0 = (const float*)d_in[9];
  p.eWih1 = (const float*)d_in[10]; p.eWhh1 = (const float*)d_in[11];
  p.ebih1 = (const float*)d_in[12]; p.ebhh1 = (const float*)d_in[13];
  p.dWih1 = (const float*)d_in[14]; p.dWhh1 = (const float*)d_in[15];
  p.dbih1 = (const float*)d_in[16]; p.dbhh1 = (const float*)d_in[17];
  p.hqW   = (const float*)d_in[18]; p.hqb   = (const float*)d_in[19];
  p.combW = (const float*)d_in[20]; p.combb = (const float*)d_in[21];
  p.fcW   = (const float*)d_in[22]; p.fcb   = (const float*)d_in[23];
  p.dout  = (float*)d_out;

  char* base = (char*)d_ws; size_t off = 0;
  auto alloc = [&](size_t bytes)->char*{
    char* r = base + off; off = (off + bytes + 255) & ~(size_t)255; return r;
  };
  p.enc_att = (uint32_t*)alloc(16777216ULL*4);     // 64 MB f16 enc_outs
  p.embh  = (_Float16*)alloc(1048576ULL*2); p.embl  = (_Float16*)alloc(1048576ULL*2);
  p.T0h   = (_Float16*)alloc(1048576ULL*2); p.T0l   = (_Float16*)alloc(1048576ULL*2);
  p.wih0dh= (_Float16*)alloc(1048576ULL*2); p.wih0dl= (_Float16*)alloc(1048576ULL*2);
  p.h0h   = (_Float16*)alloc(131072ULL*2);  p.h0l   = (_Float16*)alloc(131072ULL*2);
  p.h1h   = (_Float16*)alloc(131072ULL*2);  p.h1l   = (_Float16*)alloc(131072ULL*2);
  p.dh0h  = (_Float16*)alloc(65536ULL*2);   p.dh0l  = (_Float16*)alloc(65536ULL*2);
  p.dh1h  = (_Float16*)alloc(65536ULL*2);   p.dh1l  = (_Float16*)alloc(65536ULL*2);
  p.cath  = (_Float16*)alloc(131072ULL*2);  p.catl  = (_Float16*)alloc(131072ULL*2);
  p.ch    = (_Float16*)alloc(65536ULL*2);   p.cl    = (_Float16*)alloc(65536ULL*2);
  p.u0    = (float*)alloc(65536ULL*4);      p.u1    = (float*)alloc(65536ULL*4);
  p.q     = (float*)alloc(65536ULL*4);
  p.attp_o  = (float*)alloc(262144ULL*4);
  p.attp_ml = (float*)alloc(512ULL*4);
  p.sc63    = (float*)alloc(32768ULL*4);
  p.amax    = (unsigned long long*)alloc(16384ULL*8);  // B x 256
  { unsigned* bars = (unsigned*)alloc(16640ULL*4);
    p.ea = bars;          p.eg = bars + 8192;
    p.da = bars + 8320;   p.dg = bars + 16512; }
  if (off > ws_size) return;

  hipFuncSetAttribute(reinterpret_cast<const void*>(k_encp),
                      hipFuncAttributeMaxDynamicSharedMemorySize, ENC_LDS);
  hipFuncSetAttribute(reinterpret_cast<const void*>(k_decp),
                      hipFuncAttributeMaxDynamicSharedMemorySize, DEC_LDS);

  k_split<<<2048,256,0,stream>>>(p.emb,   p.embh,   p.embl,   1048576);
  k_split<<<2048,256,0,stream>>>(p.dWih0, p.wih0dh, p.wih0dl, 1048576);
  k_zero <<<256,256,0,stream>>>(p);
  k_t0   <<<1024,256,0,stream>>>(p);
  k_encp <<<256,512,ENC_LDS,stream>>>(p);
  k_decp <<<256,512,DEC_LDS,stream>>>(p);
}